// Round 1
// baseline (578.201 us; speedup 1.0000x reference)
//
#include <hip/hip_runtime.h>

#define B_ 64
#define N_ 2048
#define J_ 32
#define D_ 128
#define TILE_R 64
#define PAD 132          // padded LDS row stride (floats), keeps float4 alignment
#define NEG_SLOPE_ 0.2f

#define ACT_NONE 0
#define ACT_ELU 1
#define ACT_LEAKY 2

template<int ACT>
__device__ __forceinline__ float apply_act(float v) {
    if constexpr (ACT == ACT_ELU)   return v > 0.f ? v : expm1f(v);
    else if constexpr (ACT == ACT_LEAKY) return v >= 0.f ? v : NEG_SLOPE_ * v;
    else return v;
}

// Tiled [64,128] @ [128,128] fp32 GEMM + bias + activation.
// OUTMODE: 0 = ys[r][c] = act(v); 1 = ys[r][c] += act(v); 2 = store act(v) to global rows
template<int ACT, int OUTMODE>
__device__ __forceinline__ void gemm128(
    const float (*__restrict__ xs)[PAD],
    float (*__restrict__ ys)[PAD],
    float (*__restrict__ wbuf)[D_],
    const float* __restrict__ W,      // [128][128] row-major (k, n)
    const float* __restrict__ bias,   // [128]
    float bscale,
    float* __restrict__ goutb,        // out + b*N*D (OUTMODE==2)
    const int* __restrict__ rows)     // LDS row -> global op index, -1 = skip
{
    const int t = threadIdx.x;
    const int tc = t & 15;            // col group: cols tc*8 .. +7
    const int tr = t >> 4;            // row group: rows tr*4 .. +3
    float acc[4][8];
#pragma unroll
    for (int a = 0; a < 4; ++a)
#pragma unroll
        for (int c = 0; c < 8; ++c) acc[a][c] = 0.f;

    for (int k0 = 0; k0 < D_; k0 += 16) {
        __syncthreads();              // input ready / previous compute done
        {
            const int kk = t >> 4;
            const int c8 = (t & 15) * 8;
            const float* wp = W + (size_t)(k0 + kk) * D_ + c8;
            const float4 a0 = *(const float4*)wp;
            const float4 a1 = *(const float4*)(wp + 4);
            *(float4*)&wbuf[kk][c8]     = a0;
            *(float4*)&wbuf[kk][c8 + 4] = a1;
        }
        __syncthreads();
#pragma unroll
        for (int kk = 0; kk < 16; kk += 4) {
            float xk[4][4];
#pragma unroll
            for (int rr = 0; rr < 4; ++rr) {
                const float4 xv = *(const float4*)&xs[tr * 4 + rr][k0 + kk];
                xk[rr][0] = xv.x; xk[rr][1] = xv.y; xk[rr][2] = xv.z; xk[rr][3] = xv.w;
            }
#pragma unroll
            for (int q = 0; q < 4; ++q) {
                const float4 w0 = *(const float4*)&wbuf[kk + q][tc * 8];
                const float4 w1 = *(const float4*)&wbuf[kk + q][tc * 8 + 4];
#pragma unroll
                for (int rr = 0; rr < 4; ++rr) {
                    const float x = xk[rr][q];
                    acc[rr][0] += x * w0.x; acc[rr][1] += x * w0.y;
                    acc[rr][2] += x * w0.z; acc[rr][3] += x * w0.w;
                    acc[rr][4] += x * w1.x; acc[rr][5] += x * w1.y;
                    acc[rr][6] += x * w1.z; acc[rr][7] += x * w1.w;
                }
            }
        }
    }
    __syncthreads();  // all xs reads done before caller may overwrite xs

    const float* bp = bias + tc * 8;
    if constexpr (OUTMODE == 2) {
#pragma unroll
        for (int rr = 0; rr < 4; ++rr) {
            const int row = tr * 4 + rr;
            const int gi = rows[row];
            if (gi < 0) continue;
            float o[8];
#pragma unroll
            for (int c = 0; c < 8; ++c)
                o[c] = apply_act<ACT>(acc[rr][c] + bscale * bp[c]);
            float4* dst = (float4*)(goutb + (size_t)gi * D_ + tc * 8);
            dst[0] = make_float4(o[0], o[1], o[2], o[3]);
            dst[1] = make_float4(o[4], o[5], o[6], o[7]);
        }
    } else {
#pragma unroll
        for (int rr = 0; rr < 4; ++rr) {
            const int row = tr * 4 + rr;
#pragma unroll
            for (int c = 0; c < 8; ++c) {
                float v = apply_act<ACT>(acc[rr][c] + bscale * bp[c]);
                if constexpr (OUTMODE == 1) v += ys[row][tc * 8 + c];
                ys[row][tc * 8 + c] = v;
            }
        }
    }
}

// Prep: S[b][:], n_valid[b], and per-batch compacted row lists
// (updated rows, passthrough rows; valid head rows excluded — head kernel owns them)
__global__ __launch_bounds__(256) void k_prep(
    const float* __restrict__ F, const int* __restrict__ STEP,
    const int* __restrict__ ENDB, const int* __restrict__ BIDX,
    float* __restrict__ Sbuf, int* __restrict__ nvalid,
    int* __restrict__ cnt_upd, int* __restrict__ cnt_pass,
    int* __restrict__ lupd, int* __restrict__ lpass)
{
    const int b = blockIdx.x;
    const int t = threadIdx.x;
    __shared__ int steps_s[J_];
    __shared__ int valid_s[J_];
    __shared__ int cu, cp, nv;
    const int bi = BIDX[b];
    if (t == 0) { cu = 0; cp = 0; nv = 0; }
    __syncthreads();
    if (t < J_) {
        const int s = STEP[bi * J_ + t];
        const int e = ENDB[bi * J_ + t];
        steps_s[t] = s;
        const int v = (s <= e) ? 1 : 0;
        valid_s[t] = v;
        if (v) atomicAdd(&nv, 1);
    }
    __syncthreads();
    if (t < D_) {
        float acc = 0.f;
        for (int j = 0; j < J_; ++j)
            if (valid_s[j]) acc += F[((size_t)b * N_ + steps_s[j]) * D_ + t];
        Sbuf[b * D_ + t] = acc;
    }
    for (int i = t; i < N_; i += blockDim.x) {
        const bool head = (i < J_) && valid_s[i];
        if (!head) {
            const bool upd = i > steps_s[i >> 6];
            if (upd) { const int s = atomicAdd(&cu, 1); lupd[b * N_ + s] = i; }
            else     { const int s = atomicAdd(&cp, 1); lpass[b * N_ + s] = i; }
        }
    }
    __syncthreads();
    if (t == 0) { nvalid[b] = nv; cnt_upd[b] = cu; cnt_pass[b] = cp; }
}

// Body rows: DO_FW -> cand = (elu(x W1+b1)+elu(x_prev*rpow W1+b1)) W2 + 2 b2, then pr MLP.
//            !DO_FW -> pr MLP on raw features.
template<int DO_FW>
__global__ __launch_bounds__(256, 2) void k_body(
    const float* __restrict__ F, const float* __restrict__ rp_,
    const float* __restrict__ W1, const float* __restrict__ b1,
    const float* __restrict__ W2, const float* __restrict__ b2,
    const float* __restrict__ P1, const float* __restrict__ pb1,
    const float* __restrict__ P2, const float* __restrict__ pb2,
    const int* __restrict__ STEP, const int* __restrict__ BIDX,
    const int* __restrict__ cnt, const int* __restrict__ list,
    float* __restrict__ out)
{
    __shared__ float xs[TILE_R][PAD];
    __shared__ float hs[TILE_R][PAD];
    __shared__ float wbuf[16][D_];
    __shared__ int rows[TILE_R];
    const int b = blockIdx.y;
    const int c = cnt[b];
    const int r0 = blockIdx.x * TILE_R;
    if (r0 >= c) return;
    const int t = threadIdx.x;
    if (t < TILE_R) rows[t] = (r0 + t < c) ? list[b * N_ + r0 + t] : -1;
    __syncthreads();

    const float* Fb = F + (size_t)b * N_ * D_;
    float* outb = out + (size_t)b * N_ * D_;

    for (int idx = t; idx < TILE_R * 32; idx += 256) {
        const int rr = idx >> 5, c4 = (idx & 31) << 2;
        const int gi = rows[rr];
        float4 v = make_float4(0.f, 0.f, 0.f, 0.f);
        if (gi >= 0) v = *(const float4*)(Fb + (size_t)gi * D_ + c4);
        *(float4*)&xs[rr][c4] = v;
    }

    if constexpr (DO_FW) {
        gemm128<ACT_ELU, 0>(xs, hs, wbuf, W1, b1, 1.f, nullptr, nullptr);   // hs = elu(x W1+b1)
        const float r = *rp_;
        const int bi = BIDX[b];
        for (int idx = t; idx < TILE_R * 32; idx += 256) {
            const int rr = idx >> 5, c4 = (idx & 31) << 2;
            const int gi = rows[rr];
            float4 v = make_float4(0.f, 0.f, 0.f, 0.f);
            if (gi >= 0) {
                const int step = STEP[bi * J_ + (gi >> 6)];
                const float rp = powf(r, (float)(gi - step));
                const float4 f = *(const float4*)(Fb + (size_t)(gi - 1) * D_ + c4);
                v = make_float4(f.x * rp, f.y * rp, f.z * rp, f.w * rp);
            }
            *(float4*)&xs[rr][c4] = v;
        }
        gemm128<ACT_ELU, 1>(xs, hs, wbuf, W1, b1, 1.f, nullptr, nullptr);   // hs += elu(x2 W1+b1)
        gemm128<ACT_NONE, 0>(hs, xs, wbuf, W2, b2, 2.f, nullptr, nullptr);  // xs = cand
    }
    gemm128<ACT_ELU, 0>(xs, hs, wbuf, P1, pb1, 1.f, nullptr, nullptr);      // hs = elu(x P1+pb1)
    gemm128<ACT_LEAKY, 2>(hs, nullptr, wbuf, P2, pb2, 1.f, outb, rows);     // out = leaky(hs P2+pb2)
}

// Valid head rows: out[b,j] = leaky(MLP_pr(MLP_zj(mixed[b,j])))
__global__ __launch_bounds__(256, 2) void k_head(
    const float* __restrict__ F, const float* __restrict__ rp_,
    const float* __restrict__ Z1, const float* __restrict__ zb1,
    const float* __restrict__ Z2, const float* __restrict__ zb2,
    const float* __restrict__ P1, const float* __restrict__ pb1,
    const float* __restrict__ P2, const float* __restrict__ pb2,
    const int* __restrict__ STEP, const int* __restrict__ ENDB,
    const int* __restrict__ BIDX, const float* __restrict__ Sbuf,
    const int* __restrict__ nvalid, float* __restrict__ out)
{
    __shared__ float xs[TILE_R][PAD];
    __shared__ float hs[TILE_R][PAD];
    __shared__ float wbuf[16][D_];
    __shared__ int rows[TILE_R];
    __shared__ int stp[J_];
    const int b = blockIdx.x;
    const int t = threadIdx.x;
    const int bi = BIDX[b];
    if (t < J_) {
        const int s = STEP[bi * J_ + t];
        stp[t] = s;
        rows[t] = (s <= ENDB[bi * J_ + t]) ? t : -1;
    } else if (t < TILE_R) {
        rows[t] = -1;
    }
    __syncthreads();
    const float n = (float)nvalid[b];
    const float r = *rp_;
    const float inv = (n > 0.f) ? 1.f / n : 0.f;
    const float* Fb = F + (size_t)b * N_ * D_;

    for (int idx = t; idx < TILE_R * 32; idx += 256) {
        const int rr = idx >> 5, c4 = (idx & 31) << 2;
        float4 v = make_float4(0.f, 0.f, 0.f, 0.f);
        if (rr < J_ && rows[rr] >= 0) {
            const float4 cj = *(const float4*)(Fb + (size_t)stp[rr] * D_ + c4);
            const float4 Sv = *(const float4*)(Sbuf + b * D_ + c4);
            v.x = (cj.x + r * (Sv.x - cj.x)) * inv;
            v.y = (cj.y + r * (Sv.y - cj.y)) * inv;
            v.z = (cj.z + r * (Sv.z - cj.z)) * inv;
            v.w = (cj.w + r * (Sv.w - cj.w)) * inv;
        }
        *(float4*)&xs[rr][c4] = v;
    }
    gemm128<ACT_ELU, 0>(xs, hs, wbuf, Z1, zb1, 1.f, nullptr, nullptr);
    gemm128<ACT_NONE, 0>(hs, xs, wbuf, Z2, zb2, 1.f, nullptr, nullptr);
    gemm128<ACT_ELU, 0>(xs, hs, wbuf, P1, pb1, 1.f, nullptr, nullptr);
    gemm128<ACT_LEAKY, 2>(hs, nullptr, wbuf, P2, pb2, 1.f, out + (size_t)b * N_ * D_, rows);
}

extern "C" void kernel_launch(void* const* d_in, const int* in_sizes, int n_in,
                              void* d_out, int out_size, void* d_ws, size_t ws_size,
                              hipStream_t stream) {
    const float* F     = (const float*)d_in[0];
    const float* rp    = (const float*)d_in[1];
    const int*  STEP   = (const int*)d_in[2];
    const int*  ENDB   = (const int*)d_in[3];
    // d_in[4]: opes_appertain_batch — unused by the reference
    const int*  BIDX   = (const int*)d_in[5];
    const float* fwW1 = (const float*)d_in[6];
    const float* fwb1 = (const float*)d_in[7];
    const float* fwW2 = (const float*)d_in[8];
    const float* fwb2 = (const float*)d_in[9];
    const float* zjW1 = (const float*)d_in[10];
    const float* zjb1 = (const float*)d_in[11];
    const float* zjW2 = (const float*)d_in[12];
    const float* zjb2 = (const float*)d_in[13];
    const float* prW1 = (const float*)d_in[14];
    const float* prb1 = (const float*)d_in[15];
    const float* prW2 = (const float*)d_in[16];
    const float* prb2 = (const float*)d_in[17];
    float* out = (float*)d_out;

    char* ws = (char*)d_ws;
    float* Sbuf    = (float*)ws;                      // 64*128*4 = 32768 B
    int* nvalid    = (int*)(ws + 32768);              // 256 B
    int* cnt_upd   = (int*)(ws + 33024);              // 256 B
    int* cnt_pass  = (int*)(ws + 33280);              // 256 B
    int* lupd      = (int*)(ws + 33536);              // 64*2048*4 = 512 KiB
    int* lpass     = (int*)(ws + 33536 + B_ * N_ * 4);

    hipLaunchKernelGGL(k_prep, dim3(B_), dim3(256), 0, stream,
                       F, STEP, ENDB, BIDX, Sbuf, nvalid, cnt_upd, cnt_pass, lupd, lpass);
    hipLaunchKernelGGL(k_head, dim3(B_), dim3(256), 0, stream,
                       F, rp, zjW1, zjb1, zjW2, zjb2, prW1, prb1, prW2, prb2,
                       STEP, ENDB, BIDX, Sbuf, nvalid, out);
    hipLaunchKernelGGL((k_body<1>), dim3(32, B_), dim3(256), 0, stream,
                       F, rp, fwW1, fwb1, fwW2, fwb2, prW1, prb1, prW2, prb2,
                       STEP, BIDX, cnt_upd, lupd, out);
    hipLaunchKernelGGL((k_body<0>), dim3(32, B_), dim3(256), 0, stream,
                       F, rp, fwW1, fwb1, fwW2, fwb2, prW1, prb1, prW2, prb2,
                       STEP, BIDX, cnt_pass, lpass, out);
}

// Round 2
// 193.057 us; speedup vs baseline: 2.9950x; 2.9950x over previous
//
#include <hip/hip_runtime.h>

#define B_ 64
#define N_ 2048
#define J_ 32
#define D_ 128
#define TILE_R 64
#define NEG_SLOPE_ 0.2f

typedef __attribute__((ext_vector_type(4))) float f32x4;
typedef __attribute__((ext_vector_type(8))) __bf16 bf16x8;

#define ACT_NONE 0
#define ACT_ELU 1
#define ACT_LEAKY 2

template<int ACT>
__device__ __forceinline__ float apply_act(float v) {
    if constexpr (ACT == ACT_ELU)        return v > 0.f ? v : expm1f(v);
    else if constexpr (ACT == ACT_LEAKY) return v >= 0.f ? v : NEG_SLOPE_ * v;
    else return v;
}

struct TCtx { int wr, wc, ln, lq; };

// [64 x 128] (xb, bf16 swizzled) @ [128 x 128] (wb = W^T bf16 swizzled) -> acc
// wave (wr,wc): rows wr*32..+31, cols wc*64..+63; acc[m][n] is 16x16 tile
__device__ __forceinline__ void mfma_gemm64(const __bf16* __restrict__ xb,
                                            const __bf16* __restrict__ wb,
                                            const TCtx& c, f32x4 acc[2][4]) {
    const f32x4 zero = {0.f, 0.f, 0.f, 0.f};
#pragma unroll
    for (int m = 0; m < 2; ++m)
#pragma unroll
        for (int n = 0; n < 4; ++n) acc[m][n] = zero;
    const int r0 = c.wr * 32 + c.ln;
    const int r1 = r0 + 16;
#pragma unroll
    for (int ks = 0; ks < 4; ++ks) {
        const int kc = ks * 4 + c.lq;
        const bf16x8 a0 = *(const bf16x8*)&xb[r0 * D_ + ((kc ^ (r0 & 7)) << 3)];
        const bf16x8 a1 = *(const bf16x8*)&xb[r1 * D_ + ((kc ^ (r1 & 7)) << 3)];
#pragma unroll
        for (int n = 0; n < 4; ++n) {
            const int nr = c.wc * 64 + n * 16 + c.ln;
            const bf16x8 bv = *(const bf16x8*)&wb[nr * D_ + ((kc ^ (nr & 7)) << 3)];
            acc[0][n] = __builtin_amdgcn_mfma_f32_16x16x32_bf16(a0, bv, acc[0][n], 0, 0, 0);
            acc[1][n] = __builtin_amdgcn_mfma_f32_16x16x32_bf16(a1, bv, acc[1][n], 0, 0, 0);
        }
    }
}

// epilogue: act(acc + bscale*bias) -> LDS bf16 (swizzled)
template<int ACT>
__device__ __forceinline__ void epi_lds(const f32x4 acc[2][4], __bf16* dst,
                                        const float* __restrict__ bias, float bscale,
                                        const TCtx& c) {
#pragma unroll
    for (int n = 0; n < 4; ++n) {
        const int gcol = c.wc * 64 + n * 16 + c.ln;
        const float bb = bscale * bias[gcol];
        const int cc = gcol >> 3, co = gcol & 7;
#pragma unroll
        for (int m = 0; m < 2; ++m) {
#pragma unroll
            for (int rg = 0; rg < 4; ++rg) {
                const int grow = c.wr * 32 + m * 16 + c.lq * 4 + rg;
                dst[grow * D_ + ((cc ^ (grow & 7)) << 3) + co] =
                    (__bf16)apply_act<ACT>(acc[m][n][rg] + bb);
            }
        }
    }
}

// epilogue: act(acc + bias) -> global fp32 rows
template<int ACT>
__device__ __forceinline__ void epi_global(const f32x4 acc[2][4], float* __restrict__ outb,
                                           const float* __restrict__ bias,
                                           const int* __restrict__ rows, const TCtx& c) {
#pragma unroll
    for (int n = 0; n < 4; ++n) {
        const int gcol = c.wc * 64 + n * 16 + c.ln;
        const float bb = bias[gcol];
#pragma unroll
        for (int m = 0; m < 2; ++m) {
#pragma unroll
            for (int rg = 0; rg < 4; ++rg) {
                const int gi = rows[c.wr * 32 + m * 16 + c.lq * 4 + rg];
                if (gi >= 0)
                    outb[(size_t)gi * D_ + gcol] = apply_act<ACT>(acc[m][n][rg] + bb);
            }
        }
    }
}

// linear 32KB bf16 W copy (source is pre-transposed + pre-swizzled)
__device__ __forceinline__ void stage_w(__bf16* dst, const __bf16* __restrict__ src, int t) {
#pragma unroll
    for (int i = 0; i < 8; ++i) {
        const int off = (i * 256 + t) * 8;
        *(bf16x8*)&dst[off] = *(const bf16x8*)&src[off];
    }
}

// convert W [128k x 128n] fp32 -> WT[n][k] bf16, 16B-chunk XOR-swizzled
__global__ __launch_bounds__(256) void k_wprep(
    const float* __restrict__ w0, const float* __restrict__ w1,
    const float* __restrict__ w2, const float* __restrict__ w3,
    const float* __restrict__ w4, const float* __restrict__ w5,
    __bf16* __restrict__ dst) {
    const float* src;
    switch (blockIdx.x) {
        case 0: src = w0; break; case 1: src = w1; break; case 2: src = w2; break;
        case 3: src = w3; break; case 4: src = w4; break; default: src = w5; break;
    }
    __bf16* d = dst + (size_t)blockIdx.x * D_ * D_;
    for (int id = threadIdx.x; id < D_ * 16; id += 256) {
        const int n = id >> 4, ch = id & 15;
        bf16x8 u;
#pragma unroll
        for (int j = 0; j < 8; ++j) u[j] = (__bf16)src[(ch * 8 + j) * D_ + n];
        *(bf16x8*)&d[n * D_ + ((ch ^ (n & 7)) << 3)] = u;
    }
}

// prep: S[b], n_valid[b], compacted updated/passthrough row lists
__global__ __launch_bounds__(256) void k_prep(
    const float* __restrict__ F, const int* __restrict__ STEP,
    const int* __restrict__ ENDB, const int* __restrict__ BIDX,
    float* __restrict__ Sbuf, int* __restrict__ nvalid,
    int* __restrict__ cnt_upd, int* __restrict__ cnt_pass,
    unsigned short* __restrict__ lupd, unsigned short* __restrict__ lpass) {
    const int b = blockIdx.x;
    const int t = threadIdx.x;
    __shared__ int steps_s[J_];
    __shared__ int valid_s[J_];
    __shared__ int cu, cp, nv;
    const int bi = BIDX[b];
    if (t == 0) { cu = 0; cp = 0; nv = 0; }
    __syncthreads();
    if (t < J_) {
        const int s = STEP[bi * J_ + t];
        const int e = ENDB[bi * J_ + t];
        steps_s[t] = s;
        const int v = (s <= e) ? 1 : 0;
        valid_s[t] = v;
        if (v) atomicAdd(&nv, 1);
    }
    __syncthreads();
    if (t < D_) {
        float acc = 0.f;
        for (int j = 0; j < J_; ++j)
            if (valid_s[j]) acc += F[((size_t)b * N_ + steps_s[j]) * D_ + t];
        Sbuf[b * D_ + t] = acc;
    }
    for (int i = t; i < N_; i += blockDim.x) {
        const bool head = (i < J_) && valid_s[i];
        if (!head) {
            const bool upd = i > steps_s[i >> 6];
            if (upd) { const int s = atomicAdd(&cu, 1); lupd[b * N_ + s] = (unsigned short)i; }
            else     { const int s = atomicAdd(&cp, 1); lpass[b * N_ + s] = (unsigned short)i; }
        }
    }
    __syncthreads();
    if (t == 0) { nvalid[b] = nv; cnt_upd[b] = cu; cnt_pass[b] = cp; }
}

template<int DO_FW>
__global__ __launch_bounds__(256, 2) void k_body(
    const float* __restrict__ F, const float* __restrict__ rp_,
    const __bf16* __restrict__ wsW,
    const float* __restrict__ b1, const float* __restrict__ b2,
    const float* __restrict__ pb1, const float* __restrict__ pb2,
    const int* __restrict__ STEP, const int* __restrict__ BIDX,
    const int* __restrict__ cnt, const unsigned short* __restrict__ list,
    float* __restrict__ out) {
    __shared__ __bf16 xs[TILE_R * D_];
    __shared__ __bf16 hs[TILE_R * D_];
    __shared__ __bf16 wlds[D_ * D_];
    __shared__ int rows[TILE_R];
    __shared__ int stj[J_];
    __shared__ float rsc[TILE_R];

    const int b = blockIdx.y;
    const int c_ = cnt[b];
    const int r0_ = blockIdx.x * TILE_R;
    if (r0_ >= c_) return;
    const int t = threadIdx.x;
    const int lane = t & 63, wid = t >> 6;
    const TCtx tc{wid >> 1, wid & 1, lane & 15, lane >> 4};

    if (t < TILE_R) rows[t] = (r0_ + t < c_) ? (int)list[b * N_ + r0_ + t] : -1;
    if (DO_FW && t < J_) stj[t] = STEP[BIDX[b] * J_ + t];
    __syncthreads();
    const float r = *rp_;
    if (DO_FW && t < TILE_R) {
        const int gi = rows[t];
        rsc[t] = (gi >= 1) ? powf(r, (float)(gi - stj[gi >> 6])) : 0.f;
    }

    const float* Fb = F + (size_t)b * N_ * D_;
    float* outb = out + (size_t)b * N_ * D_;

    // stage xs <- x rows
    for (int id = t; id < TILE_R * 16; id += 256) {
        const int row = id >> 4, ch = id & 15;
        const int gi = rows[row];
        bf16x8 u;
        if (gi >= 0) {
            const float4 f0 = *(const float4*)(Fb + (size_t)gi * D_ + ch * 8);
            const float4 f1 = *(const float4*)(Fb + (size_t)gi * D_ + ch * 8 + 4);
            u[0] = (__bf16)f0.x; u[1] = (__bf16)f0.y; u[2] = (__bf16)f0.z; u[3] = (__bf16)f0.w;
            u[4] = (__bf16)f1.x; u[5] = (__bf16)f1.y; u[6] = (__bf16)f1.z; u[7] = (__bf16)f1.w;
        } else {
#pragma unroll
            for (int j = 0; j < 8; ++j) u[j] = (__bf16)0.f;
        }
        *(bf16x8*)&xs[row * D_ + ((ch ^ (row & 7)) << 3)] = u;
    }

    f32x4 acc[2][4];
    if constexpr (DO_FW) {
        __syncthreads();  // rsc ready (also covers xs; full sync below anyway)
        // stage hs <- x_prev * rpow
        for (int id = t; id < TILE_R * 16; id += 256) {
            const int row = id >> 4, ch = id & 15;
            const int gi = rows[row];
            bf16x8 u;
            if (gi >= 1) {
                const float s = rsc[row];
                const float4 f0 = *(const float4*)(Fb + (size_t)(gi - 1) * D_ + ch * 8);
                const float4 f1 = *(const float4*)(Fb + (size_t)(gi - 1) * D_ + ch * 8 + 4);
                u[0] = (__bf16)(f0.x * s); u[1] = (__bf16)(f0.y * s);
                u[2] = (__bf16)(f0.z * s); u[3] = (__bf16)(f0.w * s);
                u[4] = (__bf16)(f1.x * s); u[5] = (__bf16)(f1.y * s);
                u[6] = (__bf16)(f1.z * s); u[7] = (__bf16)(f1.w * s);
            } else {
#pragma unroll
                for (int j = 0; j < 8; ++j) u[j] = (__bf16)0.f;
            }
            *(bf16x8*)&hs[row * D_ + ((ch ^ (row & 7)) << 3)] = u;
        }
        stage_w(wlds, wsW + 0 * 16384, t);   // fw W1
        __syncthreads();

        f32x4 acc2[2][4];
        mfma_gemm64(xs, wlds, tc, acc);      // x @ W1
        mfma_gemm64(hs, wlds, tc, acc2);     // x2 @ W1
        __syncthreads();
        // h = elu(acc+b1) + elu(acc2+b1) -> xs ; stage W2
        stage_w(wlds, wsW + 1 * 16384, t);
#pragma unroll
        for (int n = 0; n < 4; ++n) {
            const int gcol = tc.wc * 64 + n * 16 + tc.ln;
            const float bb = b1[gcol];
            const int cc = gcol >> 3, co = gcol & 7;
#pragma unroll
            for (int m = 0; m < 2; ++m) {
#pragma unroll
                for (int rg = 0; rg < 4; ++rg) {
                    const int grow = tc.wr * 32 + m * 16 + tc.lq * 4 + rg;
                    const float v = apply_act<ACT_ELU>(acc[m][n][rg] + bb) +
                                    apply_act<ACT_ELU>(acc2[m][n][rg] + bb);
                    xs[grow * D_ + ((cc ^ (grow & 7)) << 3) + co] = (__bf16)v;
                }
            }
        }
        __syncthreads();
        mfma_gemm64(xs, wlds, tc, acc);      // h @ W2
        __syncthreads();
        epi_lds<ACT_NONE>(acc, hs, b2, 2.f, tc);   // cand -> hs
        stage_w(wlds, wsW + 2 * 16384, t);   // pr W1
        __syncthreads();
        mfma_gemm64(hs, wlds, tc, acc);      // cand @ P1
        __syncthreads();
        epi_lds<ACT_ELU>(acc, xs, pb1, 1.f, tc);   // h -> xs
        stage_w(wlds, wsW + 3 * 16384, t);   // pr W2
        __syncthreads();
        mfma_gemm64(xs, wlds, tc, acc);      // h @ P2
        epi_global<ACT_LEAKY>(acc, outb, pb2, rows, tc);
    } else {
        stage_w(wlds, wsW + 2 * 16384, t);   // pr W1
        __syncthreads();
        mfma_gemm64(xs, wlds, tc, acc);      // x @ P1
        __syncthreads();
        epi_lds<ACT_ELU>(acc, hs, pb1, 1.f, tc);
        stage_w(wlds, wsW + 3 * 16384, t);   // pr W2
        __syncthreads();
        mfma_gemm64(hs, wlds, tc, acc);      // h @ P2
        epi_global<ACT_LEAKY>(acc, outb, pb2, rows, tc);
    }
}

__global__ __launch_bounds__(256, 2) void k_head(
    const float* __restrict__ F, const float* __restrict__ rp_,
    const __bf16* __restrict__ wsW,
    const float* __restrict__ zb1, const float* __restrict__ zb2,
    const float* __restrict__ pb1, const float* __restrict__ pb2,
    const int* __restrict__ STEP, const int* __restrict__ ENDB,
    const int* __restrict__ BIDX, const float* __restrict__ Sbuf,
    const int* __restrict__ nvalid, float* __restrict__ out) {
    __shared__ __bf16 xs[TILE_R * D_];
    __shared__ __bf16 hs[TILE_R * D_];
    __shared__ __bf16 wlds[D_ * D_];
    __shared__ int rows[TILE_R];
    __shared__ int stp[J_];

    const int b = blockIdx.x;
    const int t = threadIdx.x;
    const int lane = t & 63, wid = t >> 6;
    const TCtx tc{wid >> 1, wid & 1, lane & 15, lane >> 4};
    const int bi = BIDX[b];
    if (t < J_) {
        const int s = STEP[bi * J_ + t];
        stp[t] = s;
        rows[t] = (s <= ENDB[bi * J_ + t]) ? t : -1;
    } else if (t < TILE_R) {
        rows[t] = -1;
    }
    __syncthreads();
    const float n_ = (float)nvalid[b];
    const float r = *rp_;
    const float inv = (n_ > 0.f) ? 1.f / n_ : 0.f;
    const float* Fb = F + (size_t)b * N_ * D_;

    for (int id = t; id < TILE_R * 16; id += 256) {
        const int row = id >> 4, ch = id & 15;
        bf16x8 u;
        if (row < J_ && rows[row] >= 0) {
            const float4 c0 = *(const float4*)(Fb + (size_t)stp[row] * D_ + ch * 8);
            const float4 c1 = *(const float4*)(Fb + (size_t)stp[row] * D_ + ch * 8 + 4);
            const float4 s0 = *(const float4*)(Sbuf + b * D_ + ch * 8);
            const float4 s1 = *(const float4*)(Sbuf + b * D_ + ch * 8 + 4);
            u[0] = (__bf16)((c0.x + r * (s0.x - c0.x)) * inv);
            u[1] = (__bf16)((c0.y + r * (s0.y - c0.y)) * inv);
            u[2] = (__bf16)((c0.z + r * (s0.z - c0.z)) * inv);
            u[3] = (__bf16)((c0.w + r * (s0.w - c0.w)) * inv);
            u[4] = (__bf16)((c1.x + r * (s1.x - c1.x)) * inv);
            u[5] = (__bf16)((c1.y + r * (s1.y - c1.y)) * inv);
            u[6] = (__bf16)((c1.z + r * (s1.z - c1.z)) * inv);
            u[7] = (__bf16)((c1.w + r * (s1.w - c1.w)) * inv);
        } else {
#pragma unroll
            for (int j = 0; j < 8; ++j) u[j] = (__bf16)0.f;
        }
        *(bf16x8*)&xs[row * D_ + ((ch ^ (row & 7)) << 3)] = u;
    }
    stage_w(wlds, wsW + 4 * 16384, t);   // zj W1
    __syncthreads();

    f32x4 acc[2][4];
    mfma_gemm64(xs, wlds, tc, acc);
    __syncthreads();
    epi_lds<ACT_ELU>(acc, hs, zb1, 1.f, tc);
    stage_w(wlds, wsW + 5 * 16384, t);   // zj W2
    __syncthreads();
    mfma_gemm64(hs, wlds, tc, acc);
    __syncthreads();
    epi_lds<ACT_NONE>(acc, xs, zb2, 1.f, tc);
    stage_w(wlds, wsW + 2 * 16384, t);   // pr W1
    __syncthreads();
    mfma_gemm64(xs, wlds, tc, acc);
    __syncthreads();
    epi_lds<ACT_ELU>(acc, hs, pb1, 1.f, tc);
    stage_w(wlds, wsW + 3 * 16384, t);   // pr W2
    __syncthreads();
    mfma_gemm64(hs, wlds, tc, acc);
    epi_global<ACT_LEAKY>(acc, out + (size_t)b * N_ * D_, pb2, rows, tc);
}

extern "C" void kernel_launch(void* const* d_in, const int* in_sizes, int n_in,
                              void* d_out, int out_size, void* d_ws, size_t ws_size,
                              hipStream_t stream) {
    const float* F    = (const float*)d_in[0];
    const float* rp   = (const float*)d_in[1];
    const int*  STEP  = (const int*)d_in[2];
    const int*  ENDB  = (const int*)d_in[3];
    const int*  BIDX  = (const int*)d_in[5];
    const float* fwW1 = (const float*)d_in[6];
    const float* fwb1 = (const float*)d_in[7];
    const float* fwW2 = (const float*)d_in[8];
    const float* fwb2 = (const float*)d_in[9];
    const float* zjW1 = (const float*)d_in[10];
    const float* zjb1 = (const float*)d_in[11];
    const float* zjW2 = (const float*)d_in[12];
    const float* zjb2 = (const float*)d_in[13];
    const float* prW1 = (const float*)d_in[14];
    const float* prb1 = (const float*)d_in[15];
    const float* prW2 = (const float*)d_in[16];
    const float* prb2 = (const float*)d_in[17];
    float* out = (float*)d_out;

    char* ws = (char*)d_ws;
    __bf16* wsW          = (__bf16*)ws;                       // 6*16384*2 = 393216 B
    float* Sbuf          = (float*)(ws + 393216);             // 32768 B
    int* nvalid          = (int*)(ws + 425984);               // 256 B
    int* cnt_upd         = (int*)(ws + 426240);               // 256 B
    int* cnt_pass        = (int*)(ws + 426496);               // 256 B
    unsigned short* lupd = (unsigned short*)(ws + 426752);    // 262144 B
    unsigned short* lpass= (unsigned short*)(ws + 688896);    // 262144 B

    hipLaunchKernelGGL(k_wprep, dim3(6), dim3(256), 0, stream,
                       fwW1, fwW2, prW1, prW2, zjW1, zjW2, wsW);
    hipLaunchKernelGGL(k_prep, dim3(B_), dim3(256), 0, stream,
                       F, STEP, ENDB, BIDX, Sbuf, nvalid, cnt_upd, cnt_pass, lupd, lpass);
    hipLaunchKernelGGL(k_head, dim3(B_), dim3(256), 0, stream,
                       F, rp, wsW, zjb1, zjb2, prb1, prb2,
                       STEP, ENDB, BIDX, Sbuf, nvalid, out);
    hipLaunchKernelGGL((k_body<1>), dim3(32, B_), dim3(256), 0, stream,
                       F, rp, wsW, fwb1, fwb2, prb1, prb2,
                       STEP, BIDX, cnt_upd, lupd, out);
    hipLaunchKernelGGL((k_body<0>), dim3(32, B_), dim3(256), 0, stream,
                       F, rp, wsW, fwb1, fwb2, prb1, prb2,
                       STEP, BIDX, cnt_pass, lpass, out);
}

// Round 3
// 107.041 us; speedup vs baseline: 5.4017x; 1.8036x over previous
//
#include <hip/hip_runtime.h>

#define B_ 64
#define N_ 2048
#define J_ 32
#define D_ 128
#define NEG_SLOPE_ 0.2f

typedef __attribute__((ext_vector_type(4))) float f32x4;
typedef __attribute__((ext_vector_type(8))) __bf16 bf16x8;

#define ACT_NONE 0
#define ACT_ELU 1
#define ACT_LEAKY 2

template<int ACT>
__device__ __forceinline__ float apply_act(float v) {
    if constexpr (ACT == ACT_ELU)        return v > 0.f ? v : __expf(v) - 1.f;
    else if constexpr (ACT == ACT_LEAKY) return v >= 0.f ? v : NEG_SLOPE_ * v;
    else return v;
}

struct TCtx { int wr, wc, ln, lq; };

// A [R x 128] bf16 swizzled LDS @ W^T [128 x 128] bf16 swizzled LDS.
// wave covers rows wr*32 + {0..31}, cols wc*64 + {0..63}; acc[m][n] = 16x16 tile.
__device__ __forceinline__ void mfma_gemm(const __bf16* __restrict__ xb,
                                          const __bf16* __restrict__ wb,
                                          const TCtx& c, f32x4 acc[2][4]) {
    const f32x4 zero = {0.f, 0.f, 0.f, 0.f};
#pragma unroll
    for (int m = 0; m < 2; ++m)
#pragma unroll
        for (int n = 0; n < 4; ++n) acc[m][n] = zero;
    const int r0 = c.wr * 32 + c.ln;
    const int r1 = r0 + 16;
#pragma unroll
    for (int ks = 0; ks < 4; ++ks) {
        const int kc = ks * 4 + c.lq;
        const bf16x8 a0 = *(const bf16x8*)&xb[r0 * D_ + ((kc ^ (r0 & 7)) << 3)];
        const bf16x8 a1 = *(const bf16x8*)&xb[r1 * D_ + ((kc ^ (r1 & 7)) << 3)];
#pragma unroll
        for (int n = 0; n < 4; ++n) {
            const int nr = c.wc * 64 + n * 16 + c.ln;
            const bf16x8 bv = *(const bf16x8*)&wb[nr * D_ + ((kc ^ (nr & 7)) << 3)];
            acc[0][n] = __builtin_amdgcn_mfma_f32_16x16x32_bf16(a0, bv, acc[0][n], 0, 0, 0);
            acc[1][n] = __builtin_amdgcn_mfma_f32_16x16x32_bf16(a1, bv, acc[1][n], 0, 0, 0);
        }
    }
}

// act(acc + bscale*bias) -> LDS bf16 (swizzled)
template<int ACT>
__device__ __forceinline__ void epi_lds(const f32x4 acc[2][4], __bf16* dst,
                                        const float* __restrict__ bias, float bscale,
                                        const TCtx& c) {
#pragma unroll
    for (int n = 0; n < 4; ++n) {
        const int gcol = c.wc * 64 + n * 16 + c.ln;
        const float bb = bscale * bias[gcol];
        const int cc = gcol >> 3, co = gcol & 7;
#pragma unroll
        for (int m = 0; m < 2; ++m) {
#pragma unroll
            for (int rg = 0; rg < 4; ++rg) {
                const int grow = c.wr * 32 + m * 16 + c.lq * 4 + rg;
                dst[grow * D_ + ((cc ^ (grow & 7)) << 3) + co] =
                    (__bf16)apply_act<ACT>(acc[m][n][rg] + bb);
            }
        }
    }
}

// convert W [128k x 128n] fp32 -> WT[n][k] bf16, 16B-chunk XOR-swizzled
__global__ __launch_bounds__(256) void k_wprep(
    const float* __restrict__ w0, const float* __restrict__ w1,
    const float* __restrict__ w2, const float* __restrict__ w3,
    const float* __restrict__ w4, const float* __restrict__ w5,
    __bf16* __restrict__ dst) {
    const float* src;
    switch (blockIdx.x) {
        case 0: src = w0; break; case 1: src = w1; break; case 2: src = w2; break;
        case 3: src = w3; break; case 4: src = w4; break; default: src = w5; break;
    }
    __bf16* d = dst + (size_t)blockIdx.x * D_ * D_;
    for (int id = threadIdx.x; id < D_ * 16; id += 256) {
        const int n = id >> 4, ch = id & 15;
        bf16x8 u;
#pragma unroll
        for (int j = 0; j < 8; ++j) u[j] = (__bf16)src[(ch * 8 + j) * D_ + n];
        *(bf16x8*)&d[n * D_ + ((ch ^ (n & 7)) << 3)] = u;
    }
}

// prep: S[b], n_valid[b], compacted updated list, per-row flag (1 = bf16 input in out-row)
__global__ __launch_bounds__(256) void k_prep(
    const float* __restrict__ F, const int* __restrict__ STEP,
    const int* __restrict__ ENDB, const int* __restrict__ BIDX,
    float* __restrict__ Sbuf, int* __restrict__ nvalid, int* __restrict__ cnt_upd,
    unsigned short* __restrict__ lupd, unsigned char* __restrict__ flag) {
    const int b = blockIdx.x;
    const int t = threadIdx.x;
    __shared__ int steps_s[J_];
    __shared__ int valid_s[J_];
    __shared__ int cu, nv;
    const int bi = BIDX[b];
    if (t == 0) { cu = 0; nv = 0; }
    __syncthreads();
    if (t < J_) {
        const int s = STEP[bi * J_ + t];
        const int e = ENDB[bi * J_ + t];
        steps_s[t] = s;
        const int v = (s <= e) ? 1 : 0;
        valid_s[t] = v;
        if (v) atomicAdd(&nv, 1);
    }
    __syncthreads();
    if (t < D_) {
        float acc = 0.f;
        for (int j = 0; j < J_; ++j)
            if (valid_s[j]) acc += F[((size_t)b * N_ + steps_s[j]) * D_ + t];
        Sbuf[b * D_ + t] = acc;
    }
    for (int i = t; i < N_; i += blockDim.x) {
        const bool head = (i < J_) && valid_s[i];
        unsigned char fl = 0;
        if (head) {
            fl = 1;
        } else if (i > steps_s[i >> 6]) {
            const int s = atomicAdd(&cu, 1);
            lupd[b * N_ + s] = (unsigned short)i;
            fl = 1;
        }
        flag[b * N_ + i] = fl;
    }
    __syncthreads();
    if (t == 0) { nvalid[b] = nv; cnt_upd[b] = cu; }
}

// fw MLP over updated rows: 64 upd rows/tile; xs rows 0-63 = x, rows 64-127 = x_prev*r^k.
// One W1 GEMM covers both ELU branches; W2 halves merged in f32 via mb (aliases xs).
// cand written bf16 into out rows' first 256B.
__global__ __launch_bounds__(512, 2) void k_fw(
    const float* __restrict__ F, const float* __restrict__ rp_,
    const __bf16* __restrict__ wsW,
    const float* __restrict__ b1, const float* __restrict__ b2,
    const int* __restrict__ STEP, const int* __restrict__ BIDX,
    const int* __restrict__ cnt, const unsigned short* __restrict__ list,
    float* __restrict__ out) {
    __shared__ __bf16 wlds[2 * 16384];
    __shared__ __bf16 xs[128 * D_];
    __shared__ __bf16 hs[128 * D_];
    __shared__ int rows_s[64];
    __shared__ float rsc_s[64];
    __shared__ int stj[J_];
    const int t = threadIdx.x;
    const int lane = t & 63, wid = t >> 6;
    const TCtx tc{wid >> 1, wid & 1, lane & 15, lane >> 4};
#pragma unroll
    for (int i = 0; i < 8; ++i) {
        const int off = (i * 512 + t) * 8;
        *(bf16x8*)&wlds[off] = *(const bf16x8*)&wsW[off];   // fw W1, W2
    }
    const float r = *rp_;
    float* mb = (float*)xs;   // [64][128] f32 merge buffer, alias of xs

    for (int slot = blockIdx.x; slot < B_ * 32; slot += gridDim.x) {
        const int b = slot & 63, ti = slot >> 6;
        const int c_ = cnt[b];
        const int r0_ = ti * 64;
        if (r0_ >= c_) continue;
        const int bi = BIDX[b];
        __syncthreads();   // xs/mb free from prev slot; wlds ready on first iter
        if (t < 64) rows_s[t] = (r0_ + t < c_) ? (int)list[b * N_ + r0_ + t] : -1;
        else if (t < 96) stj[t - 64] = STEP[bi * J_ + (t - 64)];
        __syncthreads();
        if (t < 64) {
            const int gi = rows_s[t];
            rsc_s[t] = (gi >= 1) ? __powf(r, (float)(gi - stj[gi >> 6])) : 0.f;
        }
        __syncthreads();
        const float* Fb = F + (size_t)b * N_ * D_;
        for (int id = t; id < 128 * 16; id += 512) {
            const int rr = id >> 4, ch = id & 15;
            bf16x8 u;
            if (rr < 64) {
                const int gi = rows_s[rr];
                if (gi >= 0) {
                    const float* fr = Fb + (size_t)gi * D_ + ch * 8;
                    const float4 f0 = *(const float4*)fr, f1 = *(const float4*)(fr + 4);
                    u[0] = (__bf16)f0.x; u[1] = (__bf16)f0.y; u[2] = (__bf16)f0.z; u[3] = (__bf16)f0.w;
                    u[4] = (__bf16)f1.x; u[5] = (__bf16)f1.y; u[6] = (__bf16)f1.z; u[7] = (__bf16)f1.w;
                } else {
#pragma unroll
                    for (int j = 0; j < 8; ++j) u[j] = (__bf16)0.f;
                }
            } else {
                const int gi = rows_s[rr - 64];
                if (gi >= 1) {
                    const float s = rsc_s[rr - 64];
                    const float* fr = Fb + (size_t)(gi - 1) * D_ + ch * 8;
                    const float4 f0 = *(const float4*)fr, f1 = *(const float4*)(fr + 4);
                    u[0] = (__bf16)(f0.x * s); u[1] = (__bf16)(f0.y * s);
                    u[2] = (__bf16)(f0.z * s); u[3] = (__bf16)(f0.w * s);
                    u[4] = (__bf16)(f1.x * s); u[5] = (__bf16)(f1.y * s);
                    u[6] = (__bf16)(f1.z * s); u[7] = (__bf16)(f1.w * s);
                } else {
#pragma unroll
                    for (int j = 0; j < 8; ++j) u[j] = (__bf16)0.f;
                }
            }
            *(bf16x8*)&xs[rr * D_ + ((ch ^ (rr & 7)) << 3)] = u;
        }
        __syncthreads();
        f32x4 acc[2][4];
        mfma_gemm(xs, wlds, tc, acc);                 // 128 rows @ W1
        epi_lds<ACT_ELU>(acc, hs, b1, 1.f, tc);       // hs = elu(. + b1), all 128 rows
        __syncthreads();
        mfma_gemm(hs, wlds + 16384, tc, acc);         // @ W2
        if (tc.wr >= 2) {                              // upper half -> merge buffer (f32)
#pragma unroll
            for (int n = 0; n < 4; ++n) {
                const int gcol = tc.wc * 64 + n * 16 + tc.ln;
#pragma unroll
                for (int m = 0; m < 2; ++m)
#pragma unroll
                    for (int rg = 0; rg < 4; ++rg) {
                        const int mrow = (tc.wr - 2) * 32 + m * 16 + tc.lq * 4 + rg;
                        mb[mrow * D_ + gcol] = acc[m][n][rg];
                    }
            }
        }
        __syncthreads();
        if (tc.wr < 2) {                               // merge + write cand bf16 into out rows
            char* outc = (char*)out + (size_t)b * N_ * 512;
#pragma unroll
            for (int n = 0; n < 4; ++n) {
                const int gcol = tc.wc * 64 + n * 16 + tc.ln;
                const float bb = 2.f * b2[gcol];
#pragma unroll
                for (int m = 0; m < 2; ++m)
#pragma unroll
                    for (int rg = 0; rg < 4; ++rg) {
                        const int row = tc.wr * 32 + m * 16 + tc.lq * 4 + rg;
                        const int gi = rows_s[row];
                        if (gi >= 0) {
                            const float cand = acc[m][n][rg] + mb[row * D_ + gcol] + bb;
                            *(__bf16*)(outc + (size_t)gi * 512 + gcol * 2) = (__bf16)cand;
                        }
                    }
            }
        }
    }
}

// head: z = MLP_zj(mixed) for valid jobs; z written bf16 into out rows' first 256B
__global__ __launch_bounds__(256, 2) void k_head(
    const float* __restrict__ F, const float* __restrict__ rp_,
    const __bf16* __restrict__ wsW,
    const float* __restrict__ zb1, const float* __restrict__ zb2,
    const int* __restrict__ STEP, const int* __restrict__ ENDB,
    const int* __restrict__ BIDX, const float* __restrict__ Sbuf,
    const int* __restrict__ nvalid, float* __restrict__ out) {
    __shared__ __bf16 wlds[2 * 16384];
    __shared__ __bf16 xs[64 * D_];
    __shared__ __bf16 hs[64 * D_];
    __shared__ int rows_s[64];
    __shared__ int stp[J_];
    const int b = blockIdx.x;
    const int t = threadIdx.x;
    const int lane = t & 63, wid = t >> 6;
    const TCtx tc{wid >> 1, wid & 1, lane & 15, lane >> 4};
#pragma unroll
    for (int i = 0; i < 16; ++i) {
        const int off = (i * 256 + t) * 8;
        *(bf16x8*)&wlds[off] = *(const bf16x8*)&wsW[4 * 16384 + off];   // zj W1, W2
    }
    const int bi = BIDX[b];
    if (t < J_) {
        const int s = STEP[bi * J_ + t];
        stp[t] = s;
        rows_s[t] = (s <= ENDB[bi * J_ + t]) ? t : -1;
    } else if (t < 64) {
        rows_s[t] = -1;
    }
    __syncthreads();
    const float n_ = (float)nvalid[b];
    const float r = *rp_;
    const float inv = (n_ > 0.f) ? 1.f / n_ : 0.f;
    const float* Fb = F + (size_t)b * N_ * D_;

    for (int id = t; id < 64 * 16; id += 256) {
        const int row = id >> 4, ch = id & 15;
        bf16x8 u;
        if (row < J_ && rows_s[row] >= 0) {
            const float4 c0 = *(const float4*)(Fb + (size_t)stp[row] * D_ + ch * 8);
            const float4 c1 = *(const float4*)(Fb + (size_t)stp[row] * D_ + ch * 8 + 4);
            const float4 s0 = *(const float4*)(Sbuf + b * D_ + ch * 8);
            const float4 s1 = *(const float4*)(Sbuf + b * D_ + ch * 8 + 4);
            u[0] = (__bf16)((c0.x + r * (s0.x - c0.x)) * inv);
            u[1] = (__bf16)((c0.y + r * (s0.y - c0.y)) * inv);
            u[2] = (__bf16)((c0.z + r * (s0.z - c0.z)) * inv);
            u[3] = (__bf16)((c0.w + r * (s0.w - c0.w)) * inv);
            u[4] = (__bf16)((c1.x + r * (s1.x - c1.x)) * inv);
            u[5] = (__bf16)((c1.y + r * (s1.y - c1.y)) * inv);
            u[6] = (__bf16)((c1.z + r * (s1.z - c1.z)) * inv);
            u[7] = (__bf16)((c1.w + r * (s1.w - c1.w)) * inv);
        } else {
#pragma unroll
            for (int j = 0; j < 8; ++j) u[j] = (__bf16)0.f;
        }
        *(bf16x8*)&xs[row * D_ + ((ch ^ (row & 7)) << 3)] = u;
    }
    __syncthreads();
    f32x4 acc[2][4];
    mfma_gemm(xs, wlds, tc, acc);
    epi_lds<ACT_ELU>(acc, hs, zb1, 1.f, tc);
    __syncthreads();
    mfma_gemm(hs, wlds + 16384, tc, acc);
    char* outc = (char*)out + (size_t)b * N_ * 512;
#pragma unroll
    for (int n = 0; n < 4; ++n) {
        const int gcol = tc.wc * 64 + n * 16 + tc.ln;
        const float bb = zb2[gcol];
#pragma unroll
        for (int m = 0; m < 2; ++m)
#pragma unroll
            for (int rg = 0; rg < 4; ++rg) {
                const int row = tc.wr * 32 + m * 16 + tc.lq * 4 + rg;
                const int gi = rows_s[row];
                if (gi >= 0)
                    *(__bf16*)(outc + (size_t)gi * 512 + gcol * 2) = (__bf16)(acc[m][n][rg] + bb);
            }
    }
}

// pr MLP over ALL rows; input = flag ? bf16 from out row : fp32 from F; out fp32 coalesced
__global__ __launch_bounds__(512, 2) void k_pr(
    const float* __restrict__ F, const unsigned char* __restrict__ flag,
    const __bf16* __restrict__ wsW,
    const float* __restrict__ pb1, const float* __restrict__ pb2,
    float* __restrict__ out) {
    __shared__ __bf16 wlds[2 * 16384];
    __shared__ __bf16 xs[128 * D_];
    __shared__ __bf16 hs[128 * D_];
    __shared__ unsigned char flg[128];
    const int t = threadIdx.x;
    const int lane = t & 63, wid = t >> 6;
    const TCtx tc{wid >> 1, wid & 1, lane & 15, lane >> 4};
#pragma unroll
    for (int i = 0; i < 8; ++i) {
        const int off = (i * 512 + t) * 8;
        *(bf16x8*)&wlds[off] = *(const bf16x8*)&wsW[2 * 16384 + off];   // pr W1, W2
    }
    for (int slot = blockIdx.x; slot < B_ * 16; slot += gridDim.x) {
        const int b = slot & 63, ti = slot >> 6;
        const int row0 = ti * 128;
        __syncthreads();   // xs/hs/flg free from prev slot; wlds ready on first iter
        if (t < 128) flg[t] = flag[b * N_ + row0 + t];
        __syncthreads();
        const float* Fb = F + ((size_t)b * N_ + row0) * D_;
        const char* candb = (const char*)out + ((size_t)b * N_ + row0) * 512;
        for (int id = t; id < 128 * 16; id += 512) {
            const int rr = id >> 4, ch = id & 15;
            bf16x8 u;
            if (flg[rr]) {
                u = *(const bf16x8*)(candb + (size_t)rr * 512 + ch * 16);
            } else {
                const float* fr = Fb + (size_t)rr * D_ + ch * 8;
                const float4 f0 = *(const float4*)fr, f1 = *(const float4*)(fr + 4);
                u[0] = (__bf16)f0.x; u[1] = (__bf16)f0.y; u[2] = (__bf16)f0.z; u[3] = (__bf16)f0.w;
                u[4] = (__bf16)f1.x; u[5] = (__bf16)f1.y; u[6] = (__bf16)f1.z; u[7] = (__bf16)f1.w;
            }
            *(bf16x8*)&xs[rr * D_ + ((ch ^ (rr & 7)) << 3)] = u;
        }
        __syncthreads();
        f32x4 acc[2][4];
        mfma_gemm(xs, wlds, tc, acc);                 // @ P1
        epi_lds<ACT_ELU>(acc, hs, pb1, 1.f, tc);
        __syncthreads();
        mfma_gemm(hs, wlds + 16384, tc, acc);         // @ P2
        float* outb = out + ((size_t)b * N_ + row0) * D_;
#pragma unroll
        for (int n = 0; n < 4; ++n) {
            const int gcol = tc.wc * 64 + n * 16 + tc.ln;
            const float bb = pb2[gcol];
#pragma unroll
            for (int m = 0; m < 2; ++m)
#pragma unroll
                for (int rg = 0; rg < 4; ++rg) {
                    const int row = tc.wr * 32 + m * 16 + tc.lq * 4 + rg;
                    outb[(size_t)row * D_ + gcol] = apply_act<ACT_LEAKY>(acc[m][n][rg] + bb);
                }
        }
    }
}

extern "C" void kernel_launch(void* const* d_in, const int* in_sizes, int n_in,
                              void* d_out, int out_size, void* d_ws, size_t ws_size,
                              hipStream_t stream) {
    const float* F    = (const float*)d_in[0];
    const float* rp   = (const float*)d_in[1];
    const int*  STEP  = (const int*)d_in[2];
    const int*  ENDB  = (const int*)d_in[3];
    const int*  BIDX  = (const int*)d_in[5];
    const float* fwW1 = (const float*)d_in[6];
    const float* fwb1 = (const float*)d_in[7];
    const float* fwW2 = (const float*)d_in[8];
    const float* fwb2 = (const float*)d_in[9];
    const float* zjW1 = (const float*)d_in[10];
    const float* zjb1 = (const float*)d_in[11];
    const float* zjW2 = (const float*)d_in[12];
    const float* zjb2 = (const float*)d_in[13];
    const float* prW1 = (const float*)d_in[14];
    const float* prb1 = (const float*)d_in[15];
    const float* prW2 = (const float*)d_in[16];
    const float* prb2 = (const float*)d_in[17];
    float* out = (float*)d_out;

    char* ws = (char*)d_ws;
    __bf16* wsW          = (__bf16*)ws;                     // 6*32768 = 393216 B
    float* Sbuf          = (float*)(ws + 393216);           // 32768 B
    int* nvalid          = (int*)(ws + 425984);             // 256 B
    int* cnt_upd         = (int*)(ws + 426240);             // 256 B
    unsigned short* lupd = (unsigned short*)(ws + 426496);  // 262144 B
    unsigned char* flag  = (unsigned char*)(ws + 688640);   // 131072 B

    hipLaunchKernelGGL(k_wprep, dim3(6), dim3(256), 0, stream,
                       fwW1, fwW2, prW1, prW2, zjW1, zjW2, wsW);
    hipLaunchKernelGGL(k_prep, dim3(B_), dim3(256), 0, stream,
                       F, STEP, ENDB, BIDX, Sbuf, nvalid, cnt_upd, lupd, flag);
    hipLaunchKernelGGL(k_head, dim3(B_), dim3(256), 0, stream,
                       F, rp, wsW, zjb1, zjb2, STEP, ENDB, BIDX, Sbuf, nvalid, out);
    hipLaunchKernelGGL(k_fw, dim3(256), dim3(512), 0, stream,
                       F, rp, wsW, fwb1, fwb2, STEP, BIDX, cnt_upd, lupd, out);
    hipLaunchKernelGGL(k_pr, dim3(256), dim3(512), 0, stream,
                       F, flag, wsW, prb1, prb2, out);
}

// Round 4
// 104.021 us; speedup vs baseline: 5.5585x; 1.0290x over previous
//
#include <hip/hip_runtime.h>

#define B_ 64
#define N_ 2048
#define J_ 32
#define D_ 128
#define NEG_SLOPE_ 0.2f

typedef __attribute__((ext_vector_type(4))) float f32x4;
typedef __attribute__((ext_vector_type(8))) __bf16 bf16x8;
typedef __attribute__((ext_vector_type(4))) __bf16 bf16x4;

#define ACT_NONE 0
#define ACT_ELU 1
#define ACT_LEAKY 2

template<int ACT>
__device__ __forceinline__ float apply_act(float v) {
    if constexpr (ACT == ACT_ELU)        return v > 0.f ? v : __expf(v) - 1.f;
    else if constexpr (ACT == ACT_LEAKY) return v >= 0.f ? v : NEG_SLOPE_ * v;
    else return v;
}

// read one bf16x8 fragment from swizzled row-major [row][128] storage
__device__ __forceinline__ bf16x8 frag_ld(const __bf16* src, int row, int kc) {
    return *(const bf16x8*)&src[row * D_ + ((kc ^ (row & 7)) << 3)];
}

// preload this wave's 64-col W^T panel (A-operand) into registers: 16 frags
__device__ __forceinline__ void load_wregs(const __bf16* __restrict__ wmat,
                                           int wcol, int ln, int lq, bf16x8 wr_[4][4]) {
#pragma unroll
    for (int ks = 0; ks < 4; ++ks)
#pragma unroll
        for (int mt = 0; mt < 4; ++mt)
            wr_[ks][mt] = frag_ld(wmat, wcol * 64 + mt * 16 + ln, ks * 4 + lq);
}

// swapped-operand GEMM: out[jr][ic] = sum_k x[jr][k] * WT[ic][k]
// A = WT panel (regs), B = x rows {jr0+ln, jr1+ln} from LDS (A-frag-style reads).
// D: lane holds out[row = jr? + (l&15)][cols ic = wcol*64 + mt*16 + lq*4 .. +3]
__device__ __forceinline__ void gemmT(const __bf16* xb, const bf16x8 wr_[4][4],
                                      int jr0, int jr1, int ln, int lq, f32x4 acc[4][2]) {
    const f32x4 z = {0.f, 0.f, 0.f, 0.f};
#pragma unroll
    for (int mt = 0; mt < 4; ++mt) { acc[mt][0] = z; acc[mt][1] = z; }
#pragma unroll
    for (int ks = 0; ks < 4; ++ks) {
        const int kc = ks * 4 + lq;
        const bf16x8 b0 = frag_ld(xb, jr0 + ln, kc);
        const bf16x8 b1 = frag_ld(xb, jr1 + ln, kc);
#pragma unroll
        for (int mt = 0; mt < 4; ++mt) {
            acc[mt][0] = __builtin_amdgcn_mfma_f32_16x16x32_bf16(wr_[ks][mt], b0, acc[mt][0], 0, 0, 0);
            acc[mt][1] = __builtin_amdgcn_mfma_f32_16x16x32_bf16(wr_[ks][mt], b1, acc[mt][1], 0, 0, 0);
        }
    }
}

// swapped-GEMM epilogue: act(acc + bias) -> swizzled LDS rows, 4 bf16 (b64) per store
template<int ACT>
__device__ __forceinline__ void epiT_lds(const f32x4 acc[4][2], __bf16* dst,
                                         const float* __restrict__ bias,
                                         int wcol, int jr0, int jr1, int ln, int lq) {
#pragma unroll
    for (int mt = 0; mt < 4; ++mt) {
        const int cb = wcol * 64 + mt * 16 + lq * 4;
        const f32x4 bv = *(const f32x4*)&bias[cb];
#pragma unroll
        for (int nt = 0; nt < 2; ++nt) {
            const int jr = (nt ? jr1 : jr0) + ln;
            bf16x4 o;
#pragma unroll
            for (int r = 0; r < 4; ++r)
                o[r] = (__bf16)apply_act<ACT>(acc[mt][nt][r] + bv[r]);
            *(bf16x4*)&dst[jr * D_ + (((cb >> 3) ^ (jr & 7)) << 3) + (cb & 7)] = o;
        }
    }
}

// ---------- legacy standard-orientation core (k_head only) ----------
struct TCtx { int wr, wc, ln, lq; };

__device__ __forceinline__ void mfma_gemm(const __bf16* __restrict__ xb,
                                          const __bf16* __restrict__ wb,
                                          const TCtx& c, f32x4 acc[2][4]) {
    const f32x4 zero = {0.f, 0.f, 0.f, 0.f};
#pragma unroll
    for (int m = 0; m < 2; ++m)
#pragma unroll
        for (int n = 0; n < 4; ++n) acc[m][n] = zero;
    const int r0 = c.wr * 32 + c.ln;
    const int r1 = r0 + 16;
#pragma unroll
    for (int ks = 0; ks < 4; ++ks) {
        const int kc = ks * 4 + c.lq;
        const bf16x8 a0 = frag_ld(xb, r0, kc);
        const bf16x8 a1 = frag_ld(xb, r1, kc);
#pragma unroll
        for (int n = 0; n < 4; ++n) {
            const int nr = c.wc * 64 + n * 16 + c.ln;
            const bf16x8 bv = frag_ld(wb, nr, kc);
            acc[0][n] = __builtin_amdgcn_mfma_f32_16x16x32_bf16(a0, bv, acc[0][n], 0, 0, 0);
            acc[1][n] = __builtin_amdgcn_mfma_f32_16x16x32_bf16(a1, bv, acc[1][n], 0, 0, 0);
        }
    }
}

template<int ACT>
__device__ __forceinline__ void epi_lds(const f32x4 acc[2][4], __bf16* dst,
                                        const float* __restrict__ bias, float bscale,
                                        const TCtx& c) {
#pragma unroll
    for (int n = 0; n < 4; ++n) {
        const int gcol = c.wc * 64 + n * 16 + c.ln;
        const float bb = bscale * bias[gcol];
        const int cc = gcol >> 3, co = gcol & 7;
#pragma unroll
        for (int m = 0; m < 2; ++m) {
#pragma unroll
            for (int rg = 0; rg < 4; ++rg) {
                const int grow = c.wr * 32 + m * 16 + c.lq * 4 + rg;
                dst[grow * D_ + ((cc ^ (grow & 7)) << 3) + co] =
                    (__bf16)apply_act<ACT>(acc[m][n][rg] + bb);
            }
        }
    }
}

// convert W [128k x 128n] fp32 -> WT[n][k] bf16, 16B-chunk XOR-swizzled
__global__ __launch_bounds__(256) void k_wprep(
    const float* __restrict__ w0, const float* __restrict__ w1,
    const float* __restrict__ w2, const float* __restrict__ w3,
    const float* __restrict__ w4, const float* __restrict__ w5,
    __bf16* __restrict__ dst) {
    const float* src;
    switch (blockIdx.x) {
        case 0: src = w0; break; case 1: src = w1; break; case 2: src = w2; break;
        case 3: src = w3; break; case 4: src = w4; break; default: src = w5; break;
    }
    __bf16* d = dst + (size_t)blockIdx.x * D_ * D_;
    for (int id = threadIdx.x; id < D_ * 16; id += 256) {
        const int n = id >> 4, ch = id & 15;
        bf16x8 u;
#pragma unroll
        for (int j = 0; j < 8; ++j) u[j] = (__bf16)src[(ch * 8 + j) * D_ + n];
        *(bf16x8*)&d[n * D_ + ((ch ^ (n & 7)) << 3)] = u;
    }
}

// prep: S[b], n_valid[b], compacted updated list + flags + flat tile queue
__global__ __launch_bounds__(256) void k_prep(
    const float* __restrict__ F, const int* __restrict__ STEP,
    const int* __restrict__ ENDB, const int* __restrict__ BIDX,
    float* __restrict__ Sbuf, int* __restrict__ nvalid, int* __restrict__ cnt_upd,
    unsigned short* __restrict__ lupd, unsigned char* __restrict__ flag,
    int* __restrict__ qcnt, int* __restrict__ queue) {
    const int b = blockIdx.x;
    const int t = threadIdx.x;
    __shared__ int steps_s[J_];
    __shared__ int valid_s[J_];
    __shared__ int cu, nv, qbase;
    const int bi = BIDX[b];
    if (t == 0) { cu = 0; nv = 0; }
    __syncthreads();
    if (t < J_) {
        const int s = STEP[bi * J_ + t];
        const int e = ENDB[bi * J_ + t];
        steps_s[t] = s;
        const int v = (s <= e) ? 1 : 0;
        valid_s[t] = v;
        if (v) atomicAdd(&nv, 1);
    }
    __syncthreads();
    if (t < D_) {
        float acc = 0.f;
        for (int j = 0; j < J_; ++j)
            if (valid_s[j]) acc += F[((size_t)b * N_ + steps_s[j]) * D_ + t];
        Sbuf[b * D_ + t] = acc;
    }
    for (int i = t; i < N_; i += blockDim.x) {
        const bool head = (i < J_) && valid_s[i];
        unsigned char fl = 0;
        if (head) {
            fl = 1;
        } else if (i > steps_s[i >> 6]) {
            const int s = atomicAdd(&cu, 1);
            lupd[b * N_ + s] = (unsigned short)i;
            fl = 1;
        }
        flag[b * N_ + i] = fl;
    }
    __syncthreads();
    const int ntile = (cu + 63) >> 6;
    if (t == 0) {
        nvalid[b] = nv;
        cnt_upd[b] = cu;
        if (ntile > 0) qbase = atomicAdd(qcnt, ntile);
    }
    __syncthreads();
    if (t < ntile) queue[qbase + t] = (b << 16) | t;
}

// fw MLP over updated rows (tile queue): xs rows 0-63 = x, 64-127 = x_prev*r^k.
// GEMM1': h(128 rows) = elu(x@W1+b1); GEMM2' with branch-pair nt mapping -> in-reg merge.
__global__ __launch_bounds__(512, 2) void k_fw(
    const float* __restrict__ F, const float* __restrict__ rp_,
    const __bf16* __restrict__ wsW,
    const float* __restrict__ b1, const float* __restrict__ b2,
    const int* __restrict__ STEP, const int* __restrict__ BIDX,
    const int* __restrict__ cnt, const unsigned short* __restrict__ list,
    const int* __restrict__ qcnt, const int* __restrict__ queue,
    float* __restrict__ out) {
    __shared__ __bf16 xs[128 * D_];
    __shared__ __bf16 hs[128 * D_];
    __shared__ int rows_s[64];
    __shared__ float rsc_s[64];
    __shared__ int stj[J_];
    const int t = threadIdx.x;
    const int ln = t & 15, lq = (t >> 4) & 3, wid = t >> 6;
    const int wcol = wid & 1, wrow = wid >> 1;
    bf16x8 w1r[4][4], w2r[4][4];
    load_wregs(wsW, wcol, ln, lq, w1r);            // fw W1^T
    load_wregs(wsW + 16384, wcol, ln, lq, w2r);    // fw W2^T
    const float r = *rp_;
    const int qn = *qcnt;

    for (int qi = blockIdx.x; qi < qn; qi += gridDim.x) {
        const int e = queue[qi];
        const int b = e >> 16, ti = e & 0xffff;
        const int c_ = cnt[b];
        const int r0_ = ti * 64;
        __syncthreads();   // xs/hs free from previous tile
        if (t < 64) rows_s[t] = (r0_ + t < c_) ? (int)list[b * N_ + r0_ + t] : -1;
        else if (t < 96) stj[t - 64] = STEP[BIDX[b] * J_ + (t - 64)];
        __syncthreads();
        if (t < 64) {
            const int gi = rows_s[t];
            rsc_s[t] = (gi >= 1) ? __powf(r, (float)(gi - stj[gi >> 6])) : 0.f;
        }
        __syncthreads();
        const float* Fb = F + (size_t)b * N_ * D_;
        for (int id = t; id < 128 * 16; id += 512) {
            const int rr = id >> 4, ch = id & 15;
            bf16x8 u;
            if (rr < 64) {
                const int gi = rows_s[rr];
                if (gi >= 0) {
                    const float* fr = Fb + (size_t)gi * D_ + ch * 8;
                    const float4 f0 = *(const float4*)fr, f1 = *(const float4*)(fr + 4);
                    u[0] = (__bf16)f0.x; u[1] = (__bf16)f0.y; u[2] = (__bf16)f0.z; u[3] = (__bf16)f0.w;
                    u[4] = (__bf16)f1.x; u[5] = (__bf16)f1.y; u[6] = (__bf16)f1.z; u[7] = (__bf16)f1.w;
                } else {
#pragma unroll
                    for (int j = 0; j < 8; ++j) u[j] = (__bf16)0.f;
                }
            } else {
                const int gi = rows_s[rr - 64];
                if (gi >= 1) {
                    const float s = rsc_s[rr - 64];
                    const float* fr = Fb + (size_t)(gi - 1) * D_ + ch * 8;
                    const float4 f0 = *(const float4*)fr, f1 = *(const float4*)(fr + 4);
                    u[0] = (__bf16)(f0.x * s); u[1] = (__bf16)(f0.y * s);
                    u[2] = (__bf16)(f0.z * s); u[3] = (__bf16)(f0.w * s);
                    u[4] = (__bf16)(f1.x * s); u[5] = (__bf16)(f1.y * s);
                    u[6] = (__bf16)(f1.z * s); u[7] = (__bf16)(f1.w * s);
                } else {
#pragma unroll
                    for (int j = 0; j < 8; ++j) u[j] = (__bf16)0.f;
                }
            }
            *(bf16x8*)&xs[rr * D_ + ((ch ^ (rr & 7)) << 3)] = u;
        }
        __syncthreads();
        f32x4 acc[4][2];
        gemmT(xs, w1r, wrow * 32, wrow * 32 + 16, ln, lq, acc);          // h = x @ W1
        epiT_lds<ACT_ELU>(acc, hs, b1, wcol, wrow * 32, wrow * 32 + 16, ln, lq);
        __syncthreads();
        gemmT(hs, w2r, wrow * 16, wrow * 16 + 64, ln, lq, acc);          // branch pair
        char* outc = (char*)out + (size_t)b * N_ * 512;
        const int gi = rows_s[wrow * 16 + ln];
        if (gi >= 0) {
#pragma unroll
            for (int mt = 0; mt < 4; ++mt) {
                const int cb = wcol * 64 + mt * 16 + lq * 4;
                const f32x4 bv = *(const f32x4*)&b2[cb];
                bf16x4 o;
#pragma unroll
                for (int rr2 = 0; rr2 < 4; ++rr2)
                    o[rr2] = (__bf16)(acc[mt][0][rr2] + acc[mt][1][rr2] + 2.f * bv[rr2]);
                *(bf16x4*)(outc + (size_t)gi * 512 + cb * 2) = o;        // cand bf16 scratch
            }
        }
    }
}

// head: z = MLP_zj(mixed) for valid jobs; z written bf16 into out rows' first 256B
__global__ __launch_bounds__(256, 2) void k_head(
    const float* __restrict__ F, const float* __restrict__ rp_,
    const __bf16* __restrict__ wsW,
    const float* __restrict__ zb1, const float* __restrict__ zb2,
    const int* __restrict__ STEP, const int* __restrict__ ENDB,
    const int* __restrict__ BIDX, const float* __restrict__ Sbuf,
    const int* __restrict__ nvalid, float* __restrict__ out) {
    __shared__ __bf16 wlds[2 * 16384];
    __shared__ __bf16 xs[64 * D_];
    __shared__ __bf16 hs[64 * D_];
    __shared__ int rows_s[64];
    __shared__ int stp[J_];
    const int b = blockIdx.x;
    const int t = threadIdx.x;
    const int lane = t & 63, wid = t >> 6;
    const TCtx tc{wid >> 1, wid & 1, lane & 15, lane >> 4};
#pragma unroll
    for (int i = 0; i < 16; ++i) {
        const int off = (i * 256 + t) * 8;
        *(bf16x8*)&wlds[off] = *(const bf16x8*)&wsW[4 * 16384 + off];   // zj W1, W2
    }
    const int bi = BIDX[b];
    if (t < J_) {
        const int s = STEP[bi * J_ + t];
        stp[t] = s;
        rows_s[t] = (s <= ENDB[bi * J_ + t]) ? t : -1;
    } else if (t < 64) {
        rows_s[t] = -1;
    }
    __syncthreads();
    const float n_ = (float)nvalid[b];
    const float r = *rp_;
    const float inv = (n_ > 0.f) ? 1.f / n_ : 0.f;
    const float* Fb = F + (size_t)b * N_ * D_;

    for (int id = t; id < 64 * 16; id += 256) {
        const int row = id >> 4, ch = id & 15;
        bf16x8 u;
        if (row < J_ && rows_s[row] >= 0) {
            const float4 c0 = *(const float4*)(Fb + (size_t)stp[row] * D_ + ch * 8);
            const float4 c1 = *(const float4*)(Fb + (size_t)stp[row] * D_ + ch * 8 + 4);
            const float4 s0 = *(const float4*)(Sbuf + b * D_ + ch * 8);
            const float4 s1 = *(const float4*)(Sbuf + b * D_ + ch * 8 + 4);
            u[0] = (__bf16)((c0.x + r * (s0.x - c0.x)) * inv);
            u[1] = (__bf16)((c0.y + r * (s0.y - c0.y)) * inv);
            u[2] = (__bf16)((c0.z + r * (s0.z - c0.z)) * inv);
            u[3] = (__bf16)((c0.w + r * (s0.w - c0.w)) * inv);
            u[4] = (__bf16)((c1.x + r * (s1.x - c1.x)) * inv);
            u[5] = (__bf16)((c1.y + r * (s1.y - c1.y)) * inv);
            u[6] = (__bf16)((c1.z + r * (s1.z - c1.z)) * inv);
            u[7] = (__bf16)((c1.w + r * (s1.w - c1.w)) * inv);
        } else {
#pragma unroll
            for (int j = 0; j < 8; ++j) u[j] = (__bf16)0.f;
        }
        *(bf16x8*)&xs[row * D_ + ((ch ^ (row & 7)) << 3)] = u;
    }
    __syncthreads();
    f32x4 acc[2][4];
    mfma_gemm(xs, wlds, tc, acc);
    epi_lds<ACT_ELU>(acc, hs, zb1, 1.f, tc);
    __syncthreads();
    mfma_gemm(hs, wlds + 16384, tc, acc);
    char* outc = (char*)out + (size_t)b * N_ * 512;
#pragma unroll
    for (int n = 0; n < 4; ++n) {
        const int gcol = tc.wc * 64 + n * 16 + tc.ln;
        const float bb = zb2[gcol];
#pragma unroll
        for (int m = 0; m < 2; ++m)
#pragma unroll
            for (int rg = 0; rg < 4; ++rg) {
                const int row = tc.wr * 32 + m * 16 + tc.lq * 4 + rg;
                const int gi = rows_s[row];
                if (gi >= 0)
                    *(__bf16*)(outc + (size_t)gi * 512 + gcol * 2) = (__bf16)(acc[m][n][rg] + bb);
            }
    }
}

// pr MLP over ALL rows; input = flag ? bf16 cand/z from out row : fp32 from F
__global__ __launch_bounds__(512, 2) void k_pr(
    const float* __restrict__ F, const unsigned char* __restrict__ flag,
    const __bf16* __restrict__ wsW,
    const float* __restrict__ pb1, const float* __restrict__ pb2,
    float* __restrict__ out) {
    __shared__ __bf16 xs[128 * D_];
    __shared__ __bf16 hs[128 * D_];
    __shared__ unsigned char flg[128];
    const int t = threadIdx.x;
    const int ln = t & 15, lq = (t >> 4) & 3, wid = t >> 6;
    const int wcol = wid & 1, wrow = wid >> 1;
    bf16x8 w1r[4][4], w2r[4][4];
    load_wregs(wsW + 2 * 16384, wcol, ln, lq, w1r);    // pr W1^T
    load_wregs(wsW + 3 * 16384, wcol, ln, lq, w2r);    // pr W2^T

    for (int slot = blockIdx.x; slot < B_ * 16; slot += gridDim.x) {
        const int b = slot & 63, ti = slot >> 6;
        const int row0 = ti * 128;
        __syncthreads();   // xs/hs/flg free from previous slot
        if (t < 128) flg[t] = flag[b * N_ + row0 + t];
        __syncthreads();
        const float* Fb = F + ((size_t)b * N_ + row0) * D_;
        const char* candb = (const char*)out + ((size_t)b * N_ + row0) * 512;
        for (int id = t; id < 128 * 16; id += 512) {
            const int rr = id >> 4, ch = id & 15;
            bf16x8 u;
            if (flg[rr]) {
                u = *(const bf16x8*)(candb + (size_t)rr * 512 + ch * 16);
            } else {
                const float* fr = Fb + (size_t)rr * D_ + ch * 8;
                const float4 f0 = *(const float4*)fr, f1 = *(const float4*)(fr + 4);
                u[0] = (__bf16)f0.x; u[1] = (__bf16)f0.y; u[2] = (__bf16)f0.z; u[3] = (__bf16)f0.w;
                u[4] = (__bf16)f1.x; u[5] = (__bf16)f1.y; u[6] = (__bf16)f1.z; u[7] = (__bf16)f1.w;
            }
            *(bf16x8*)&xs[rr * D_ + ((ch ^ (rr & 7)) << 3)] = u;
        }
        __syncthreads();
        f32x4 acc[4][2];
        gemmT(xs, w1r, wrow * 32, wrow * 32 + 16, ln, lq, acc);          // @ P1
        epiT_lds<ACT_ELU>(acc, hs, pb1, wcol, wrow * 32, wrow * 32 + 16, ln, lq);
        __syncthreads();
        gemmT(hs, w2r, wrow * 32, wrow * 32 + 16, ln, lq, acc);          // @ P2
        float* outb = out + ((size_t)b * N_ + row0) * D_;
#pragma unroll
        for (int mt = 0; mt < 4; ++mt) {
            const int cb = wcol * 64 + mt * 16 + lq * 4;
            const f32x4 bv = *(const f32x4*)&pb2[cb];
#pragma unroll
            for (int nt = 0; nt < 2; ++nt) {
                const int jr = wrow * 32 + nt * 16 + ln;
                f32x4 o;
#pragma unroll
                for (int rr2 = 0; rr2 < 4; ++rr2)
                    o[rr2] = apply_act<ACT_LEAKY>(acc[mt][nt][rr2] + bv[rr2]);
                *(f32x4*)&outb[(size_t)jr * D_ + cb] = o;
            }
        }
    }
}

extern "C" void kernel_launch(void* const* d_in, const int* in_sizes, int n_in,
                              void* d_out, int out_size, void* d_ws, size_t ws_size,
                              hipStream_t stream) {
    const float* F    = (const float*)d_in[0];
    const float* rp   = (const float*)d_in[1];
    const int*  STEP  = (const int*)d_in[2];
    const int*  ENDB  = (const int*)d_in[3];
    const int*  BIDX  = (const int*)d_in[5];
    const float* fwW1 = (const float*)d_in[6];
    const float* fwb1 = (const float*)d_in[7];
    const float* fwW2 = (const float*)d_in[8];
    const float* fwb2 = (const float*)d_in[9];
    const float* zjW1 = (const float*)d_in[10];
    const float* zjb1 = (const float*)d_in[11];
    const float* zjW2 = (const float*)d_in[12];
    const float* zjb2 = (const float*)d_in[13];
    const float* prW1 = (const float*)d_in[14];
    const float* prb1 = (const float*)d_in[15];
    const float* prW2 = (const float*)d_in[16];
    const float* prb2 = (const float*)d_in[17];
    float* out = (float*)d_out;

    char* ws = (char*)d_ws;
    __bf16* wsW          = (__bf16*)ws;                     // 393216 B
    float* Sbuf          = (float*)(ws + 393216);           // 32768 B
    int* nvalid          = (int*)(ws + 425984);             // 256 B
    int* cnt_upd         = (int*)(ws + 426240);             // 256 B
    unsigned short* lupd = (unsigned short*)(ws + 426496);  // 262144 B
    unsigned char* flag  = (unsigned char*)(ws + 688640);   // 131072 B
    int* qcnt            = (int*)(ws + 819712);             // 256 B
    int* queue           = (int*)(ws + 819968);             // 8192 B

    hipMemsetAsync(qcnt, 0, 4, stream);
    hipLaunchKernelGGL(k_wprep, dim3(6), dim3(256), 0, stream,
                       fwW1, fwW2, prW1, prW2, zjW1, zjW2, wsW);
    hipLaunchKernelGGL(k_prep, dim3(B_), dim3(256), 0, stream,
                       F, STEP, ENDB, BIDX, Sbuf, nvalid, cnt_upd, lupd, flag, qcnt, queue);
    hipLaunchKernelGGL(k_head, dim3(B_), dim3(256), 0, stream,
                       F, rp, wsW, zjb1, zjb2, STEP, ENDB, BIDX, Sbuf, nvalid, out);
    hipLaunchKernelGGL(k_fw, dim3(256), dim3(512), 0, stream,
                       F, rp, wsW, fwb1, fwb2, STEP, BIDX, cnt_upd, lupd, qcnt, queue, out);
    hipLaunchKernelGGL(k_pr, dim3(256), dim3(512), 0, stream,
                       F, flag, wsW, prb1, prb2, out);
}

// Round 5
// 103.231 us; speedup vs baseline: 5.6011x; 1.0077x over previous
//
#include <hip/hip_runtime.h>

#define B_ 64
#define N_ 2048
#define J_ 32
#define D_ 128
#define NEG_SLOPE_ 0.2f

typedef __attribute__((ext_vector_type(4))) float f32x4;
typedef __attribute__((ext_vector_type(8))) __bf16 bf16x8;
typedef __attribute__((ext_vector_type(4))) __bf16 bf16x4;

#define ACT_NONE 0
#define ACT_ELU 1
#define ACT_LEAKY 2

template<int ACT>
__device__ __forceinline__ float apply_act(float v) {
    if constexpr (ACT == ACT_ELU)        return v > 0.f ? v : __expf(v) - 1.f;
    else if constexpr (ACT == ACT_LEAKY) return v >= 0.f ? v : NEG_SLOPE_ * v;
    else return v;
}

// read one bf16x8 fragment from swizzled row-major [row][128] storage
__device__ __forceinline__ bf16x8 frag_ld(const __bf16* src, int row, int kc) {
    return *(const bf16x8*)&src[row * D_ + ((kc ^ (row & 7)) << 3)];
}

// preload this wave's 64-col W^T panel (A-operand) into registers: 16 frags
__device__ __forceinline__ void load_wregs(const __bf16* __restrict__ wmat,
                                           int wcol, int ln, int lq, bf16x8 wr_[4][4]) {
#pragma unroll
    for (int ks = 0; ks < 4; ++ks)
#pragma unroll
        for (int mt = 0; mt < 4; ++mt)
            wr_[ks][mt] = frag_ld(wmat, wcol * 64 + mt * 16 + ln, ks * 4 + lq);
}

// swapped-operand GEMM: out[jr][ic] = sum_k x[jr][k] * WT[ic][k]
// A = WT panel (regs), B = x rows {jr0+ln, jr1+ln} from LDS (A-frag-style reads).
// D: lane holds out[row = jr? + (l&15)][cols ic = wcol*64 + mt*16 + lq*4 .. +3]
__device__ __forceinline__ void gemmT(const __bf16* xb, const bf16x8 wr_[4][4],
                                      int jr0, int jr1, int ln, int lq, f32x4 acc[4][2]) {
    const f32x4 z = {0.f, 0.f, 0.f, 0.f};
#pragma unroll
    for (int mt = 0; mt < 4; ++mt) { acc[mt][0] = z; acc[mt][1] = z; }
#pragma unroll
    for (int ks = 0; ks < 4; ++ks) {
        const int kc = ks * 4 + lq;
        const bf16x8 b0 = frag_ld(xb, jr0 + ln, kc);
        const bf16x8 b1 = frag_ld(xb, jr1 + ln, kc);
#pragma unroll
        for (int mt = 0; mt < 4; ++mt) {
            acc[mt][0] = __builtin_amdgcn_mfma_f32_16x16x32_bf16(wr_[ks][mt], b0, acc[mt][0], 0, 0, 0);
            acc[mt][1] = __builtin_amdgcn_mfma_f32_16x16x32_bf16(wr_[ks][mt], b1, acc[mt][1], 0, 0, 0);
        }
    }
}

// swapped-GEMM epilogue: act(acc + bias) -> swizzled LDS rows, 4 bf16 (b64) per store
template<int ACT>
__device__ __forceinline__ void epiT_lds(const f32x4 acc[4][2], __bf16* dst,
                                         const float* __restrict__ bias,
                                         int wcol, int jr0, int jr1, int ln, int lq) {
#pragma unroll
    for (int mt = 0; mt < 4; ++mt) {
        const int cb = wcol * 64 + mt * 16 + lq * 4;
        const f32x4 bv = *(const f32x4*)&bias[cb];
#pragma unroll
        for (int nt = 0; nt < 2; ++nt) {
            const int jr = (nt ? jr1 : jr0) + ln;
            bf16x4 o;
#pragma unroll
            for (int r = 0; r < 4; ++r)
                o[r] = (__bf16)apply_act<ACT>(acc[mt][nt][r] + bv[r]);
            *(bf16x4*)&dst[jr * D_ + (((cb >> 3) ^ (jr & 7)) << 3) + (cb & 7)] = o;
        }
    }
}

// ---------- legacy standard-orientation core (k_head only) ----------
struct TCtx { int wr, wc, ln, lq; };

__device__ __forceinline__ void mfma_gemm(const __bf16* __restrict__ xb,
                                          const __bf16* __restrict__ wb,
                                          const TCtx& c, f32x4 acc[2][4]) {
    const f32x4 zero = {0.f, 0.f, 0.f, 0.f};
#pragma unroll
    for (int m = 0; m < 2; ++m)
#pragma unroll
        for (int n = 0; n < 4; ++n) acc[m][n] = zero;
    const int r0 = c.wr * 32 + c.ln;
    const int r1 = r0 + 16;
#pragma unroll
    for (int ks = 0; ks < 4; ++ks) {
        const int kc = ks * 4 + c.lq;
        const bf16x8 a0 = frag_ld(xb, r0, kc);
        const bf16x8 a1 = frag_ld(xb, r1, kc);
#pragma unroll
        for (int n = 0; n < 4; ++n) {
            const int nr = c.wc * 64 + n * 16 + c.ln;
            const bf16x8 bv = frag_ld(wb, nr, kc);
            acc[0][n] = __builtin_amdgcn_mfma_f32_16x16x32_bf16(a0, bv, acc[0][n], 0, 0, 0);
            acc[1][n] = __builtin_amdgcn_mfma_f32_16x16x32_bf16(a1, bv, acc[1][n], 0, 0, 0);
        }
    }
}

template<int ACT>
__device__ __forceinline__ void epi_lds(const f32x4 acc[2][4], __bf16* dst,
                                        const float* __restrict__ bias, float bscale,
                                        const TCtx& c) {
#pragma unroll
    for (int n = 0; n < 4; ++n) {
        const int gcol = c.wc * 64 + n * 16 + c.ln;
        const float bb = bscale * bias[gcol];
        const int cc = gcol >> 3, co = gcol & 7;
#pragma unroll
        for (int m = 0; m < 2; ++m) {
#pragma unroll
            for (int rg = 0; rg < 4; ++rg) {
                const int grow = c.wr * 32 + m * 16 + c.lq * 4 + rg;
                dst[grow * D_ + ((cc ^ (grow & 7)) << 3) + co] =
                    (__bf16)apply_act<ACT>(acc[m][n][rg] + bb);
            }
        }
    }
}

// merged prep: blocks 0-5 convert W fp32 -> WT bf16 swizzled; blocks 6-69 do per-batch prep
__global__ __launch_bounds__(256) void k_prep(
    const float* __restrict__ w0, const float* __restrict__ w1,
    const float* __restrict__ w2, const float* __restrict__ w3,
    const float* __restrict__ w4, const float* __restrict__ w5,
    __bf16* __restrict__ wdst,
    const float* __restrict__ F, const int* __restrict__ STEP,
    const int* __restrict__ ENDB, const int* __restrict__ BIDX,
    float* __restrict__ Sbuf, int* __restrict__ nvalid, int* __restrict__ cnt_upd,
    unsigned short* __restrict__ lupd, unsigned char* __restrict__ flag,
    int* __restrict__ qcnt, int* __restrict__ queue) {
    const int t = threadIdx.x;
    if (blockIdx.x < 6) {
        const float* src;
        switch (blockIdx.x) {
            case 0: src = w0; break; case 1: src = w1; break; case 2: src = w2; break;
            case 3: src = w3; break; case 4: src = w4; break; default: src = w5; break;
        }
        __bf16* d = wdst + (size_t)blockIdx.x * D_ * D_;
        for (int id = t; id < D_ * 16; id += 256) {
            const int n = id >> 4, ch = id & 15;
            bf16x8 u;
#pragma unroll
            for (int j = 0; j < 8; ++j) u[j] = (__bf16)src[(ch * 8 + j) * D_ + n];
            *(bf16x8*)&d[n * D_ + ((ch ^ (n & 7)) << 3)] = u;
        }
        return;
    }
    const int b = blockIdx.x - 6;
    __shared__ int steps_s[J_];
    __shared__ int valid_s[J_];
    __shared__ int cu, nv, qbase;
    const int bi = BIDX[b];
    if (t == 0) { cu = 0; nv = 0; }
    __syncthreads();
    if (t < J_) {
        const int s = STEP[bi * J_ + t];
        const int e = ENDB[bi * J_ + t];
        steps_s[t] = s;
        const int v = (s <= e) ? 1 : 0;
        valid_s[t] = v;
        if (v) atomicAdd(&nv, 1);
    }
    __syncthreads();
    if (t < D_) {
        float acc = 0.f;
        for (int j = 0; j < J_; ++j)
            if (valid_s[j]) acc += F[((size_t)b * N_ + steps_s[j]) * D_ + t];
        Sbuf[b * D_ + t] = acc;
    }
    for (int i = t; i < N_; i += blockDim.x) {
        const bool head = (i < J_) && valid_s[i];
        unsigned char fl = 0;
        if (head) {
            fl = 1;
        } else if (i > steps_s[i >> 6]) {
            const int s = atomicAdd(&cu, 1);
            lupd[b * N_ + s] = (unsigned short)i;
            fl = 1;
        }
        flag[b * N_ + i] = fl;
    }
    __syncthreads();
    const int ntile = (cu + 63) >> 6;
    if (t == 0) {
        nvalid[b] = nv;
        cnt_upd[b] = cu;
        if (ntile > 0) qbase = atomicAdd(qcnt, ntile);
    }
    __syncthreads();
    if (t < ntile) queue[qbase + t] = (b << 16) | t;
}

// fw MLP over updated rows (tile queue): xs rows 0-63 = x, 64-127 = x_prev*r^k.
__global__ __launch_bounds__(512, 2) void k_fw(
    const float* __restrict__ F, const float* __restrict__ rp_,
    const __bf16* __restrict__ wsW,
    const float* __restrict__ b1, const float* __restrict__ b2,
    const int* __restrict__ STEP, const int* __restrict__ BIDX,
    const int* __restrict__ cnt, const unsigned short* __restrict__ list,
    const int* __restrict__ qcnt, const int* __restrict__ queue,
    float* __restrict__ out) {
    __shared__ __bf16 xs[128 * D_];
    __shared__ __bf16 hs[128 * D_];
    __shared__ int rows_s[64];
    __shared__ float rsc_s[64];
    __shared__ int stj[J_];
    const int t = threadIdx.x;
    const int ln = t & 15, lq = (t >> 4) & 3, wid = t >> 6;
    const int wcol = wid & 1, wrow = wid >> 1;
    bf16x8 w1r[4][4], w2r[4][4];
    load_wregs(wsW, wcol, ln, lq, w1r);            // fw W1^T
    load_wregs(wsW + 16384, wcol, ln, lq, w2r);    // fw W2^T
    const float r = *rp_;
    const int qn = *qcnt;

    for (int qi = blockIdx.x; qi < qn; qi += gridDim.x) {
        const int e = queue[qi];
        const int b = e >> 16, ti = e & 0xffff;
        const int c_ = cnt[b];
        const int r0_ = ti * 64;
        __syncthreads();   // xs/hs free from previous tile
        if (t < 64) rows_s[t] = (r0_ + t < c_) ? (int)list[b * N_ + r0_ + t] : -1;
        else if (t < 96) stj[t - 64] = STEP[BIDX[b] * J_ + (t - 64)];
        __syncthreads();
        if (t < 64) {
            const int gi = rows_s[t];
            rsc_s[t] = (gi >= 1) ? __powf(r, (float)(gi - stj[gi >> 6])) : 0.f;
        }
        __syncthreads();
        const float* Fb = F + (size_t)b * N_ * D_;
        for (int id = t; id < 128 * 16; id += 512) {
            const int rr = id >> 4, ch = id & 15;
            bf16x8 u;
            if (rr < 64) {
                const int gi = rows_s[rr];
                if (gi >= 0) {
                    const float* fr = Fb + (size_t)gi * D_ + ch * 8;
                    const float4 f0 = *(const float4*)fr, f1 = *(const float4*)(fr + 4);
                    u[0] = (__bf16)f0.x; u[1] = (__bf16)f0.y; u[2] = (__bf16)f0.z; u[3] = (__bf16)f0.w;
                    u[4] = (__bf16)f1.x; u[5] = (__bf16)f1.y; u[6] = (__bf16)f1.z; u[7] = (__bf16)f1.w;
                } else {
#pragma unroll
                    for (int j = 0; j < 8; ++j) u[j] = (__bf16)0.f;
                }
            } else {
                const int gi = rows_s[rr - 64];
                if (gi >= 1) {
                    const float s = rsc_s[rr - 64];
                    const float* fr = Fb + (size_t)(gi - 1) * D_ + ch * 8;
                    const float4 f0 = *(const float4*)fr, f1 = *(const float4*)(fr + 4);
                    u[0] = (__bf16)(f0.x * s); u[1] = (__bf16)(f0.y * s);
                    u[2] = (__bf16)(f0.z * s); u[3] = (__bf16)(f0.w * s);
                    u[4] = (__bf16)(f1.x * s); u[5] = (__bf16)(f1.y * s);
                    u[6] = (__bf16)(f1.z * s); u[7] = (__bf16)(f1.w * s);
                } else {
#pragma unroll
                    for (int j = 0; j < 8; ++j) u[j] = (__bf16)0.f;
                }
            }
            *(bf16x8*)&xs[rr * D_ + ((ch ^ (rr & 7)) << 3)] = u;
        }
        __syncthreads();
        f32x4 acc[4][2];
        gemmT(xs, w1r, wrow * 32, wrow * 32 + 16, ln, lq, acc);          // h = x @ W1
        epiT_lds<ACT_ELU>(acc, hs, b1, wcol, wrow * 32, wrow * 32 + 16, ln, lq);
        __syncthreads();
        gemmT(hs, w2r, wrow * 16, wrow * 16 + 64, ln, lq, acc);          // branch pair
        char* outc = (char*)out + (size_t)b * N_ * 512;
        const int gi = rows_s[wrow * 16 + ln];
        if (gi >= 0) {
#pragma unroll
            for (int mt = 0; mt < 4; ++mt) {
                const int cb = wcol * 64 + mt * 16 + lq * 4;
                const f32x4 bv = *(const f32x4*)&b2[cb];
                bf16x4 o;
#pragma unroll
                for (int rr2 = 0; rr2 < 4; ++rr2)
                    o[rr2] = (__bf16)(acc[mt][0][rr2] + acc[mt][1][rr2] + 2.f * bv[rr2]);
                *(bf16x4*)(outc + (size_t)gi * 512 + cb * 2) = o;        // cand bf16 scratch
            }
        }
    }
}

// head: z = MLP_zj(mixed) for valid jobs; z written bf16 into out rows' first 256B
__global__ __launch_bounds__(256, 2) void k_head(
    const float* __restrict__ F, const float* __restrict__ rp_,
    const __bf16* __restrict__ wsW,
    const float* __restrict__ zb1, const float* __restrict__ zb2,
    const int* __restrict__ STEP, const int* __restrict__ ENDB,
    const int* __restrict__ BIDX, const float* __restrict__ Sbuf,
    const int* __restrict__ nvalid, float* __restrict__ out) {
    __shared__ __bf16 wlds[2 * 16384];
    __shared__ __bf16 xs[64 * D_];
    __shared__ __bf16 hs[64 * D_];
    __shared__ int rows_s[64];
    __shared__ int stp[J_];
    const int b = blockIdx.x;
    const int t = threadIdx.x;
    const int lane = t & 63, wid = t >> 6;
    const TCtx tc{wid >> 1, wid & 1, lane & 15, lane >> 4};
#pragma unroll
    for (int i = 0; i < 16; ++i) {
        const int off = (i * 256 + t) * 8;
        *(bf16x8*)&wlds[off] = *(const bf16x8*)&wsW[4 * 16384 + off];   // zj W1, W2
    }
    const int bi = BIDX[b];
    if (t < J_) {
        const int s = STEP[bi * J_ + t];
        stp[t] = s;
        rows_s[t] = (s <= ENDB[bi * J_ + t]) ? t : -1;
    } else if (t < 64) {
        rows_s[t] = -1;
    }
    __syncthreads();
    const float n_ = (float)nvalid[b];
    const float r = *rp_;
    const float inv = (n_ > 0.f) ? 1.f / n_ : 0.f;
    const float* Fb = F + (size_t)b * N_ * D_;

    for (int id = t; id < 64 * 16; id += 256) {
        const int row = id >> 4, ch = id & 15;
        bf16x8 u;
        if (row < J_ && rows_s[row] >= 0) {
            const float4 c0 = *(const float4*)(Fb + (size_t)stp[row] * D_ + ch * 8);
            const float4 c1 = *(const float4*)(Fb + (size_t)stp[row] * D_ + ch * 8 + 4);
            const float4 s0 = *(const float4*)(Sbuf + b * D_ + ch * 8);
            const float4 s1 = *(const float4*)(Sbuf + b * D_ + ch * 8 + 4);
            u[0] = (__bf16)((c0.x + r * (s0.x - c0.x)) * inv);
            u[1] = (__bf16)((c0.y + r * (s0.y - c0.y)) * inv);
            u[2] = (__bf16)((c0.z + r * (s0.z - c0.z)) * inv);
            u[3] = (__bf16)((c0.w + r * (s0.w - c0.w)) * inv);
            u[4] = (__bf16)((c1.x + r * (s1.x - c1.x)) * inv);
            u[5] = (__bf16)((c1.y + r * (s1.y - c1.y)) * inv);
            u[6] = (__bf16)((c1.z + r * (s1.z - c1.z)) * inv);
            u[7] = (__bf16)((c1.w + r * (s1.w - c1.w)) * inv);
        } else {
#pragma unroll
            for (int j = 0; j < 8; ++j) u[j] = (__bf16)0.f;
        }
        *(bf16x8*)&xs[row * D_ + ((ch ^ (row & 7)) << 3)] = u;
    }
    __syncthreads();
    f32x4 acc[2][4];
    mfma_gemm(xs, wlds, tc, acc);
    epi_lds<ACT_ELU>(acc, hs, zb1, 1.f, tc);
    __syncthreads();
    mfma_gemm(hs, wlds + 16384, tc, acc);
    char* outc = (char*)out + (size_t)b * N_ * 512;
#pragma unroll
    for (int n = 0; n < 4; ++n) {
        const int gcol = tc.wc * 64 + n * 16 + tc.ln;
        const float bb = zb2[gcol];
#pragma unroll
        for (int m = 0; m < 2; ++m)
#pragma unroll
            for (int rg = 0; rg < 4; ++rg) {
                const int row = tc.wr * 32 + m * 16 + tc.lq * 4 + rg;
                const int gi = rows_s[row];
                if (gi >= 0)
                    *(__bf16*)(outc + (size_t)gi * 512 + gcol * 2) = (__bf16)(acc[m][n][rg] + bb);
            }
    }
}

// pr MLP over ALL rows; input = flag ? bf16 cand/z from out row : fp32 from F
__global__ __launch_bounds__(512, 2) void k_pr(
    const float* __restrict__ F, const unsigned char* __restrict__ flag,
    const __bf16* __restrict__ wsW,
    const float* __restrict__ pb1, const float* __restrict__ pb2,
    float* __restrict__ out) {
    __shared__ __bf16 xs[128 * D_];
    __shared__ __bf16 hs[128 * D_];
    __shared__ unsigned char flg[128];
    const int t = threadIdx.x;
    const int ln = t & 15, lq = (t >> 4) & 3, wid = t >> 6;
    const int wcol = wid & 1, wrow = wid >> 1;
    bf16x8 w1r[4][4], w2r[4][4];
    load_wregs(wsW + 2 * 16384, wcol, ln, lq, w1r);    // pr W1^T
    load_wregs(wsW + 3 * 16384, wcol, ln, lq, w2r);    // pr W2^T

    for (int slot = blockIdx.x; slot < B_ * 16; slot += gridDim.x) {
        const int b = slot & 63, ti = slot >> 6;
        const int row0 = ti * 128;
        __syncthreads();   // xs/hs/flg free from previous slot
        if (t < 128) flg[t] = flag[b * N_ + row0 + t];
        __syncthreads();
        const float* Fb = F + ((size_t)b * N_ + row0) * D_;
        const char* candb = (const char*)out + ((size_t)b * N_ + row0) * 512;
        for (int id = t; id < 128 * 16; id += 512) {
            const int rr = id >> 4, ch = id & 15;
            bf16x8 u;
            if (flg[rr]) {
                u = *(const bf16x8*)(candb + (size_t)rr * 512 + ch * 16);
            } else {
                const float* fr = Fb + (size_t)rr * D_ + ch * 8;
                const float4 f0 = *(const float4*)fr, f1 = *(const float4*)(fr + 4);
                u[0] = (__bf16)f0.x; u[1] = (__bf16)f0.y; u[2] = (__bf16)f0.z; u[3] = (__bf16)f0.w;
                u[4] = (__bf16)f1.x; u[5] = (__bf16)f1.y; u[6] = (__bf16)f1.z; u[7] = (__bf16)f1.w;
            }
            *(bf16x8*)&xs[rr * D_ + ((ch ^ (rr & 7)) << 3)] = u;
        }
        __syncthreads();
        f32x4 acc[4][2];
        gemmT(xs, w1r, wrow * 32, wrow * 32 + 16, ln, lq, acc);          // @ P1
        epiT_lds<ACT_ELU>(acc, hs, pb1, wcol, wrow * 32, wrow * 32 + 16, ln, lq);
        __syncthreads();
        gemmT(hs, w2r, wrow * 32, wrow * 32 + 16, ln, lq, acc);          // @ P2
        float* outb = out + ((size_t)b * N_ + row0) * D_;
#pragma unroll
        for (int mt = 0; mt < 4; ++mt) {
            const int cb = wcol * 64 + mt * 16 + lq * 4;
            const f32x4 bv = *(const f32x4*)&pb2[cb];
#pragma unroll
            for (int nt = 0; nt < 2; ++nt) {
                const int jr = wrow * 32 + nt * 16 + ln;
                f32x4 o;
#pragma unroll
                for (int rr2 = 0; rr2 < 4; ++rr2)
                    o[rr2] = apply_act<ACT_LEAKY>(acc[mt][nt][rr2] + bv[rr2]);
                *(f32x4*)&outb[(size_t)jr * D_ + cb] = o;
            }
        }
    }
}

extern "C" void kernel_launch(void* const* d_in, const int* in_sizes, int n_in,
                              void* d_out, int out_size, void* d_ws, size_t ws_size,
                              hipStream_t stream) {
    const float* F    = (const float*)d_in[0];
    const float* rp   = (const float*)d_in[1];
    const int*  STEP  = (const int*)d_in[2];
    const int*  ENDB  = (const int*)d_in[3];
    const int*  BIDX  = (const int*)d_in[5];
    const float* fwW1 = (const float*)d_in[6];
    const float* fwb1 = (const float*)d_in[7];
    const float* fwW2 = (const float*)d_in[8];
    const float* fwb2 = (const float*)d_in[9];
    const float* zjW1 = (const float*)d_in[10];
    const float* zjb1 = (const float*)d_in[11];
    const float* zjW2 = (const float*)d_in[12];
    const float* zjb2 = (const float*)d_in[13];
    const float* prW1 = (const float*)d_in[14];
    const float* prb1 = (const float*)d_in[15];
    const float* prW2 = (const float*)d_in[16];
    const float* prb2 = (const float*)d_in[17];
    float* out = (float*)d_out;

    char* ws = (char*)d_ws;
    __bf16* wsW          = (__bf16*)ws;                     // 393216 B
    float* Sbuf          = (float*)(ws + 393216);           // 32768 B
    int* nvalid          = (int*)(ws + 425984);             // 256 B
    int* cnt_upd         = (int*)(ws + 426240);             // 256 B
    unsigned short* lupd = (unsigned short*)(ws + 426496);  // 262144 B
    unsigned char* flag  = (unsigned char*)(ws + 688640);   // 131072 B
    int* qcnt            = (int*)(ws + 819712);             // 256 B
    int* queue           = (int*)(ws + 819968);             // 8192 B

    hipMemsetAsync(qcnt, 0, 4, stream);
    hipLaunchKernelGGL(k_prep, dim3(70), dim3(256), 0, stream,
                       fwW1, fwW2, prW1, prW2, zjW1, zjW2, wsW,
                       F, STEP, ENDB, BIDX, Sbuf, nvalid, cnt_upd, lupd, flag, qcnt, queue);
    hipLaunchKernelGGL(k_head, dim3(B_), dim3(256), 0, stream,
                       F, rp, wsW, zjb1, zjb2, STEP, ENDB, BIDX, Sbuf, nvalid, out);
    hipLaunchKernelGGL(k_fw, dim3(512), dim3(512), 0, stream,
                       F, rp, wsW, fwb1, fwb2, STEP, BIDX, cnt_upd, lupd, qcnt, queue, out);
    hipLaunchKernelGGL(k_pr, dim3(512), dim3(512), 0, stream,
                       F, flag, wsW, prb1, prb2, out);
}